// Round 1
// baseline (12550.182 us; speedup 1.0000x reference)
//
#include <hip/hip_runtime.h>
#include <hip/hip_bf16.h>
#include <cstddef>

// Model dims (fixed by the reference)
#define VOCAB 50257
#define DMODEL 1024
#define NHEAD 8
#define NLAYER 6
#define SEQ 1024
#define BATCH 2
#define HDIM 128
#define FFDIM 4096
#define NTOK (SEQ * BATCH)   // 2048 tokens
#define EPSV 1e-5f

// ---------------------------------------------------------------------------
// Embedding: x[s,b,d] = tok_emb[tokens[s,b], d] + pos_emb[s, d]
// ---------------------------------------------------------------------------
__global__ __launch_bounds__(256) void embed_kernel(
    const int* __restrict__ tokens, const float* __restrict__ tok_emb,
    const float* __restrict__ pos_emb, float* __restrict__ x)
{
    int idx = blockIdx.x * 256 + threadIdx.x;      // over NTOK*DMODEL
    int t = idx >> 10;                             // token index = s*BATCH+b
    int d = idx & (DMODEL - 1);
    int s = t >> 1;                                // BATCH == 2
    int tok = tokens[t];
    x[idx] = tok_emb[(size_t)tok * DMODEL + d] + pos_emb[(size_t)s * DMODEL + d];
}

// ---------------------------------------------------------------------------
// RMSNorm: one block (256 thr) per token row of D=1024; float4 per thread.
// ---------------------------------------------------------------------------
__global__ __launch_bounds__(256) void rmsnorm_kernel(
    const float* __restrict__ x, const float* __restrict__ w, float* __restrict__ o)
{
    int t = blockIdx.x;
    int tid = threadIdx.x;
    const float4 xv = ((const float4*)(x + (size_t)t * DMODEL))[tid];
    float ss = xv.x * xv.x + xv.y * xv.y + xv.z * xv.z + xv.w * xv.w;
    __shared__ float red[256];
    red[tid] = ss;
    __syncthreads();
    for (int off = 128; off > 0; off >>= 1) {
        if (tid < off) red[tid] += red[tid + off];
        __syncthreads();
    }
    float inv = rsqrtf(red[0] * (1.0f / DMODEL) + EPSV);
    const float4 wv = ((const float4*)w)[tid];
    float4 ov;
    ov.x = wv.x * xv.x * inv;
    ov.y = wv.y * xv.y * inv;
    ov.z = wv.z * xv.z * inv;
    ov.w = wv.w * xv.w * inv;
    ((float4*)(o + (size_t)t * DMODEL))[tid] = ov;
}

// ---------------------------------------------------------------------------
// Tiled f32 GEMM, 64x64 tile, BK=16, 256 threads, 4x4 per thread.
// BMODE: 0 = NN (B is K x N row-major, ldb)
//        1 = NT (B is N x K row-major, ldb)   [lm_head vs tok_emb]
//        2 = HEADS (B is [h][K][128]; column c maps to head c>>7, col c&127)
// ACC: C += result; SILU: apply x*sigmoid(x) before store.
// Requirements: M % 64 == 0, K % 16 == 0, lda/ldb % 4 == 0. N tail guarded.
// ---------------------------------------------------------------------------
template<int BMODE, bool ACC, bool SILU>
__global__ __launch_bounds__(256) void gemm_kernel(
    const float* __restrict__ A, const float* __restrict__ Bp, float* __restrict__ C,
    int M, int N, int K, int lda, int ldb, int ldc)
{
    __shared__ float As[16][64 + 4];
    __shared__ float Bs[16][64 + 4];
    const int tid = threadIdx.x;
    const int tx = tid & 15, ty = tid >> 4;
    const int row0 = blockIdx.y * 64;
    const int col0 = blockIdx.x * 64;

    const float* Bbase = Bp;
    int colb = col0;
    int ldbe = ldb;
    if (BMODE == 2) {
        Bbase = Bp + (size_t)(col0 >> 7) * K * 128;
        colb = col0 & 127;
        ldbe = 128;
    }

    float acc[4][4] = {};

    for (int k0 = 0; k0 < K; k0 += 16) {
        // A tile: each thread does one float4 along K, transposed store.
        {
            int e = tid * 4;
            int m = e >> 4, kk = e & 15;
            float4 av = *(const float4*)(A + (size_t)(row0 + m) * lda + k0 + kk);
            As[kk + 0][m] = av.x;
            As[kk + 1][m] = av.y;
            As[kk + 2][m] = av.z;
            As[kk + 3][m] = av.w;
        }
        if (BMODE == 1) {
            int e = tid * 4;
            int c = e >> 4, kk = e & 15;
            int gc = col0 + c;
            float4 bv = make_float4(0.f, 0.f, 0.f, 0.f);
            if (gc < N) bv = *(const float4*)(Bbase + (size_t)gc * ldb + k0 + kk);
            Bs[kk + 0][c] = bv.x;
            Bs[kk + 1][c] = bv.y;
            Bs[kk + 2][c] = bv.z;
            Bs[kk + 3][c] = bv.w;
        } else {
            int e = tid * 4;
            int kk = e >> 6, c = e & 63;
            float4 bv = *(const float4*)(Bbase + (size_t)(k0 + kk) * ldbe + colb + c);
            *(float4*)&Bs[kk][c] = bv;   // row stride 68 floats -> 16B aligned
        }
        __syncthreads();

        #pragma unroll
        for (int kk = 0; kk < 16; kk++) {
            float a[4], b[4];
            #pragma unroll
            for (int i = 0; i < 4; i++) a[i] = As[kk][ty * 4 + i];
            #pragma unroll
            for (int j = 0; j < 4; j++) b[j] = Bs[kk][tx * 4 + j];
            #pragma unroll
            for (int i = 0; i < 4; i++)
                #pragma unroll
                for (int j = 0; j < 4; j++) acc[i][j] += a[i] * b[j];
        }
        __syncthreads();
    }

    #pragma unroll
    for (int i = 0; i < 4; i++) {
        int r = row0 + ty * 4 + i;
        #pragma unroll
        for (int j = 0; j < 4; j++) {
            int c = col0 + tx * 4 + j;
            if (c < N) {
                float vv = acc[i][j];
                if (SILU) vv = vv / (1.0f + __expf(-vv));
                if (ACC) C[(size_t)r * ldc + c] += vv;
                else     C[(size_t)r * ldc + c] = vv;
            }
        }
    }
}

// ---------------------------------------------------------------------------
// Attention: one block (256 thr) per (query row s_q, head h, batch b).
// q/k/v layout: [token t = s*BATCH+b][h*HDIM + d]  (NTOK x 1024)
// Two-pass softmax over keys 0..s_q in LDS.
// ---------------------------------------------------------------------------
__global__ __launch_bounds__(256) void attn_kernel(
    const float* __restrict__ q, const float* __restrict__ k,
    const float* __restrict__ v, float* __restrict__ o)
{
    const int s_q = blockIdx.x;
    const int h   = blockIdx.y;
    const int b   = blockIdx.z;
    const int tid = threadIdx.x;
    const int tq  = s_q * BATCH + b;

    __shared__ float qs[HDIM];
    __shared__ float sc[SEQ];
    __shared__ float red[256];
    __shared__ float obuf[2][HDIM];

    if (tid < HDIM) qs[tid] = q[(size_t)tq * DMODEL + h * HDIM + tid];
    __syncthreads();

    // scores for keys 0..s_q
    const float scale = 0.08838834764831845f;   // 1/sqrt(128)
    for (int t = tid; t <= s_q; t += 256) {
        const float* kr = k + (size_t)(t * BATCH + b) * DMODEL + h * HDIM;
        float d = 0.f;
        #pragma unroll 8
        for (int i = 0; i < HDIM; i++) d += qs[i] * kr[i];
        sc[t] = d * scale;
    }
    __syncthreads();

    // max
    float m = -1e30f;
    for (int t = tid; t <= s_q; t += 256) m = fmaxf(m, sc[t]);
    red[tid] = m;
    __syncthreads();
    for (int off = 128; off > 0; off >>= 1) {
        if (tid < off) red[tid] = fmaxf(red[tid], red[tid + off]);
        __syncthreads();
    }
    m = red[0];
    __syncthreads();

    // exp + sum
    float sum = 0.f;
    for (int t = tid; t <= s_q; t += 256) {
        float p = __expf(sc[t] - m);
        sc[t] = p;
        sum += p;
    }
    red[tid] = sum;
    __syncthreads();
    for (int off = 128; off > 0; off >>= 1) {
        if (tid < off) red[tid] += red[tid + off];
        __syncthreads();
    }
    float inv = 1.0f / red[0];

    // weighted sum of V: 2 halves over keys, 128 d-lanes each
    int d = tid & (HDIM - 1);
    int half = tid >> 7;
    float acc = 0.f;
    for (int t = half; t <= s_q; t += 2)
        acc += sc[t] * v[(size_t)(t * BATCH + b) * DMODEL + h * HDIM + d];
    obuf[half][d] = acc;
    __syncthreads();
    if (tid < HDIM)
        o[(size_t)tq * DMODEL + h * HDIM + tid] = (obuf[0][tid] + obuf[1][tid]) * inv;
}

// ---------------------------------------------------------------------------
// Launch
// ---------------------------------------------------------------------------
extern "C" void kernel_launch(void* const* d_in, const int* in_sizes, int n_in,
                              void* d_out, int out_size, void* d_ws, size_t ws_size,
                              hipStream_t stream)
{
    const int*   tokens       = (const int*)  d_in[0];
    const float* tok_emb      = (const float*)d_in[1];
    const float* pos_emb      = (const float*)d_in[2];
    const float* attn_norm_w  = (const float*)d_in[3];
    const float* Wq           = (const float*)d_in[4];   // (L,H,D,HD)
    const float* Wk           = (const float*)d_in[5];
    const float* Wv           = (const float*)d_in[6];
    const float* Wo           = (const float*)d_in[7];   // (L,H,HD,D) == (L, H*HD, D)
    const float* mlp_norm_w   = (const float*)d_in[8];
    const float* W1           = (const float*)d_in[9];   // (L,D,FF)
    const float* W2           = (const float*)d_in[10];  // (L,FF,D)
    const float* final_norm_w = (const float*)d_in[11];
    float* out = (float*)d_out;                           // (S,B,V) f32

    // Workspace layout (floats). Total = 6*2M + 8M = 20M floats = 80 MB.
    float* x    = (float*)d_ws;
    float* n    = x    + (size_t)NTOK * DMODEL;
    float* q    = n    + (size_t)NTOK * DMODEL;
    float* kbuf = q    + (size_t)NTOK * DMODEL;
    float* vbuf = kbuf + (size_t)NTOK * DMODEL;
    float* attn = vbuf + (size_t)NTOK * DMODEL;
    float* hbuf = attn + (size_t)NTOK * DMODEL;           // NTOK x FF

    const size_t LWqkv = (size_t)NHEAD * DMODEL * HDIM;   // per-layer W{q,k,v,o} elems
    const size_t LW1   = (size_t)DMODEL * FFDIM;
    const size_t LW2   = (size_t)FFDIM * DMODEL;

    // x = embed
    embed_kernel<<<(NTOK * DMODEL) / 256, 256, 0, stream>>>(tokens, tok_emb, pos_emb, x);

    dim3 g_d(DMODEL / 64, NTOK / 64);     // 16 x 32
    dim3 g_ff(FFDIM / 64, NTOK / 64);     // 64 x 32

    for (int l = 0; l < NLAYER; l++) {
        // attn rmsnorm
        rmsnorm_kernel<<<NTOK, 256, 0, stream>>>(x, attn_norm_w + (size_t)l * DMODEL, n);
        // q,k,v projections (HEADS mode)
        gemm_kernel<2, false, false><<<g_d, 256, 0, stream>>>(
            n, Wq + (size_t)l * LWqkv, q, NTOK, DMODEL, DMODEL, DMODEL, 128, DMODEL);
        gemm_kernel<2, false, false><<<g_d, 256, 0, stream>>>(
            n, Wk + (size_t)l * LWqkv, kbuf, NTOK, DMODEL, DMODEL, DMODEL, 128, DMODEL);
        gemm_kernel<2, false, false><<<g_d, 256, 0, stream>>>(
            n, Wv + (size_t)l * LWqkv, vbuf, NTOK, DMODEL, DMODEL, DMODEL, 128, DMODEL);
        // attention
        attn_kernel<<<dim3(SEQ, NHEAD, BATCH), 256, 0, stream>>>(q, kbuf, vbuf, attn);
        // out proj (+ residual): x += attn @ Wo[l]  (Wo[l] viewed as (H*HD, D) row-major)
        gemm_kernel<0, true, false><<<g_d, 256, 0, stream>>>(
            attn, Wo + (size_t)l * LWqkv, x, NTOK, DMODEL, DMODEL, DMODEL, DMODEL, DMODEL);
        // mlp rmsnorm
        rmsnorm_kernel<<<NTOK, 256, 0, stream>>>(x, mlp_norm_w + (size_t)l * DMODEL, n);
        // h = silu(n @ W1)
        gemm_kernel<0, false, true><<<g_ff, 256, 0, stream>>>(
            n, W1 + (size_t)l * LW1, hbuf, NTOK, FFDIM, DMODEL, DMODEL, FFDIM, FFDIM);
        // x += h @ W2
        gemm_kernel<0, true, false><<<g_d, 256, 0, stream>>>(
            hbuf, W2 + (size_t)l * LW2, x, NTOK, DMODEL, FFDIM, FFDIM, DMODEL, DMODEL);
    }

    // final norm
    rmsnorm_kernel<<<NTOK, 256, 0, stream>>>(x, final_norm_w, n);
    // logits = n @ tok_emb^T  (NT), N = VOCAB with tail guard
    dim3 g_v((VOCAB + 63) / 64, NTOK / 64);  // 786 x 32
    gemm_kernel<1, false, false><<<g_v, 256, 0, stream>>>(
        n, tok_emb, out, NTOK, VOCAB, DMODEL, DMODEL, DMODEL, VOCAB);
}

// Round 3
// 7058.546 us; speedup vs baseline: 1.7780x; 1.7780x over previous
//
#include <hip/hip_runtime.h>
#include <hip/hip_bf16.h>
#include <cstddef>
#include <cstdint>

// Model dims (fixed by the reference)
#define VOCAB 50257
#define VPAD  50304              // 393 * 128
#define DMODEL 1024
#define NHEAD 8
#define NLAYER 6
#define SEQ 1024
#define BATCH 2
#define HDIM 128
#define FFDIM 4096
#define NTOK (SEQ * BATCH)       // 2048 tokens
#define EPSV 1e-5f

typedef __attribute__((ext_vector_type(8))) short short8;
typedef __attribute__((ext_vector_type(4))) float f32x4;

__device__ __forceinline__ unsigned short f2bf(float f) {
    union { float f; unsigned u; } v; v.f = f;
    unsigned r = v.u + 0x7FFF + ((v.u >> 16) & 1);   // round-to-nearest-even
    return (unsigned short)(r >> 16);
}

// ---------------------------------------------------------------------------
// Embedding: x[s,b,d] = tok_emb[tokens[s,b], d] + pos_emb[s, d]   (f32)
// ---------------------------------------------------------------------------
__global__ __launch_bounds__(256) void embed_kernel(
    const int* __restrict__ tokens, const float* __restrict__ tok_emb,
    const float* __restrict__ pos_emb, float* __restrict__ x)
{
    int idx = blockIdx.x * 256 + threadIdx.x;
    int t = idx >> 10;
    int d = idx & (DMODEL - 1);
    int s = t >> 1;                       // BATCH == 2
    int tok = tokens[t];
    x[idx] = tok_emb[(size_t)tok * DMODEL + d] + pos_emb[(size_t)s * DMODEL + d];
}

// ---------------------------------------------------------------------------
// RMSNorm f32 -> bf16 out. One block per token row (D=1024), float4/thread.
// ---------------------------------------------------------------------------
__global__ __launch_bounds__(256) void rmsnorm_bf_kernel(
    const float* __restrict__ x, const float* __restrict__ w,
    unsigned short* __restrict__ o)
{
    int t = blockIdx.x;
    int tid = threadIdx.x;
    const float4 xv = ((const float4*)(x + (size_t)t * DMODEL))[tid];
    float ss = xv.x * xv.x + xv.y * xv.y + xv.z * xv.z + xv.w * xv.w;
    __shared__ float red[256];
    red[tid] = ss;
    __syncthreads();
    for (int off = 128; off > 0; off >>= 1) {
        if (tid < off) red[tid] += red[tid + off];
        __syncthreads();
    }
    float inv = rsqrtf(red[0] * (1.0f / DMODEL) + EPSV);
    const float4 wv = ((const float4*)w)[tid];
    ushort4 ov;
    ov.x = f2bf(wv.x * xv.x * inv);
    ov.y = f2bf(wv.y * xv.y * inv);
    ov.z = f2bf(wv.z * xv.z * inv);
    ov.w = f2bf(wv.w * xv.w * inv);
    ((ushort4*)(o + (size_t)t * DMODEL))[tid] = ov;
}

// ---------------------------------------------------------------------------
// Batched transpose + f32->bf16 cast: in [batch][R][C] f32 -> out [batch][C][R] bf16
// Block (32,8); grid (C/32, R/32, batch).
// ---------------------------------------------------------------------------
__global__ __launch_bounds__(256) void transpose_cast_kernel(
    const float* __restrict__ in, unsigned short* __restrict__ out, int R, int C)
{
    __shared__ float tile[32][33];
    const size_t bo = (size_t)blockIdx.z * R * C;
    const float* src = in + bo;
    unsigned short* dst = out + bo;
    int c0 = blockIdx.x * 32, r0 = blockIdx.y * 32;
    int tx = threadIdx.x, ty = threadIdx.y;
    #pragma unroll
    for (int i = 0; i < 32; i += 8)
        tile[ty + i][tx] = src[(size_t)(r0 + ty + i) * C + c0 + tx];
    __syncthreads();
    #pragma unroll
    for (int i = 0; i < 32; i += 8)
        dst[(size_t)(c0 + ty + i) * R + r0 + tx] = f2bf(tile[tx][ty + i]);
}

// ---------------------------------------------------------------------------
// f32 -> bf16 flat cast with zero padding (for tok_emb -> [VPAD][D] bf16).
// 8 elements per thread.
// ---------------------------------------------------------------------------
__global__ __launch_bounds__(256) void cast_pad_kernel(
    const float* __restrict__ in, unsigned short* __restrict__ out,
    long n_src, long n_tot)
{
    long i = ((long)blockIdx.x * 256 + threadIdx.x) * 8;
    if (i >= n_tot) return;
    short8 o8;
    if (i < n_src) {
        const float4* p = (const float4*)(in + i);
        float4 a = p[0], b = p[1];
        o8[0] = (short)f2bf(a.x); o8[1] = (short)f2bf(a.y);
        o8[2] = (short)f2bf(a.z); o8[3] = (short)f2bf(a.w);
        o8[4] = (short)f2bf(b.x); o8[5] = (short)f2bf(b.y);
        o8[6] = (short)f2bf(b.z); o8[7] = (short)f2bf(b.w);
    } else {
        o8 = (short8)0;
    }
    *(short8*)(out + i) = o8;
}

// ---------------------------------------------------------------------------
// bf16 MFMA GEMM (m97 structure): C[M][N] = A[M][K] * Bt[N][K]^T
// 128x128 tile, BK=32, 256 threads (4 waves, each a 64x64 quadrant of 4x4
// 16x16x32 fragments). global_load_lds width-16 staging, single LDS buffer,
// 2 barriers per K-step. M%128==0, K%32==0; Bt must have ceil(N/128)*128 rows.
// ACC: C += (f32). SILU: x*sigmoid(x). BF16OUT: store bf16, else f32.
// ---------------------------------------------------------------------------
template<bool ACC, bool SILU, bool BF16OUT>
__global__ __launch_bounds__(256) void mm_kernel(
    const unsigned short* __restrict__ A, const unsigned short* __restrict__ Bt,
    void* __restrict__ Cv, int M, int N, int K)
{
    __shared__ unsigned short lds[8192];   // A: elems [0,4096), B: [4096,8192)
    const int tid  = threadIdx.x;
    const int lane = tid & 63;
    const int wave = tid >> 6;
    const int wm = wave >> 1, wn = wave & 1;
    const int row0 = blockIdx.y * 128;
    const int col0 = blockIdx.x * 128;

    f32x4 acc[4][4] = {};

    const int off_base = wave * 4096 + lane * 16;  // byte offset in combined 16KB region
    const int kfr = (lane >> 4) * 8;               // fragment k offset
    const int l15 = lane & 15;

    for (int k0 = 0; k0 < K; k0 += 32) {
        #pragma unroll
        for (int c = 0; c < 4; ++c) {
            int off  = off_base + c * 1024;
            int row  = (off & 8191) >> 6;          // row within the 128-row tile
            int koff = (off >> 1) & 31;            // k element offset within BK
            const unsigned short* src = (off < 8192)
                ? A  + (size_t)(row0 + row) * K + k0 + koff
                : Bt + (size_t)(col0 + row) * K + k0 + koff;
            unsigned short* dst = lds + ((wave * 4096 + c * 1024) >> 1);
            __builtin_amdgcn_global_load_lds(
                (const __attribute__((address_space(1))) void*)src,
                (__attribute__((address_space(3))) void*)dst, 16, 0, 0);
        }
        __syncthreads();

        short8 af[4], bfr[4];
        #pragma unroll
        for (int i = 0; i < 4; ++i)
            af[i] = *(const short8*)&lds[(wm * 64 + i * 16 + l15) * 32 + kfr];
        #pragma unroll
        for (int j = 0; j < 4; ++j)
            bfr[j] = *(const short8*)&lds[4096 + (wn * 64 + j * 16 + l15) * 32 + kfr];
        #pragma unroll
        for (int i = 0; i < 4; ++i)
            #pragma unroll
            for (int j = 0; j < 4; ++j)
                acc[i][j] = __builtin_amdgcn_mfma_f32_16x16x32_bf16(
                    af[i], bfr[j], acc[i][j], 0, 0, 0);
        __syncthreads();
    }

    float* Cf = (float*)Cv;
    unsigned short* Cb = (unsigned short*)Cv;
    const int crow  = row0 + wm * 64 + ((lane >> 4) << 2);
    const int ccol0 = col0 + wn * 64 + l15;
    #pragma unroll
    for (int i = 0; i < 4; ++i) {
        #pragma unroll
        for (int j = 0; j < 4; ++j) {
            int gcol = ccol0 + j * 16;
            if (gcol < N) {
                #pragma unroll
                for (int r = 0; r < 4; ++r) {
                    int grow = crow + i * 16 + r;
                    float v = acc[i][j][r];
                    if (SILU) v = v / (1.0f + __expf(-v));
                    size_t ci = (size_t)grow * N + gcol;
                    if (BF16OUT)      Cb[ci] = f2bf(v);
                    else if (ACC)     Cf[ci] += v;
                    else              Cf[ci] = v;
                }
            }
        }
    }
}

// ---------------------------------------------------------------------------
// Attention: one block (256 thr) per (query row s_q, head h, batch b).
// q/k/v f32 [token][h*128+d]; out bf16.
// ---------------------------------------------------------------------------
__global__ __launch_bounds__(256) void attn_kernel2(
    const float* __restrict__ q, const float* __restrict__ k,
    const float* __restrict__ v, unsigned short* __restrict__ o)
{
    const int s_q = blockIdx.x;
    const int h   = blockIdx.y;
    const int b   = blockIdx.z;
    const int tid = threadIdx.x;
    const int tq  = s_q * BATCH + b;

    __shared__ float qs[HDIM];
    __shared__ float sc[SEQ];
    __shared__ float red[256];
    __shared__ float obuf[2][HDIM];

    if (tid < HDIM) qs[tid] = q[(size_t)tq * DMODEL + h * HDIM + tid];
    __syncthreads();

    const float scale = 0.08838834764831845f;
    for (int t = tid; t <= s_q; t += 256) {
        const float* kr = k + (size_t)(t * BATCH + b) * DMODEL + h * HDIM;
        float d = 0.f;
        #pragma unroll 8
        for (int i = 0; i < HDIM; i++) d += qs[i] * kr[i];
        sc[t] = d * scale;
    }
    __syncthreads();

    float m = -1e30f;
    for (int t = tid; t <= s_q; t += 256) m = fmaxf(m, sc[t]);
    red[tid] = m;
    __syncthreads();
    for (int off = 128; off > 0; off >>= 1) {
        if (tid < off) red[tid] = fmaxf(red[tid], red[tid + off]);
        __syncthreads();
    }
    m = red[0];
    __syncthreads();

    float sum = 0.f;
    for (int t = tid; t <= s_q; t += 256) {
        float p = __expf(sc[t] - m);
        sc[t] = p;
        sum += p;
    }
    red[tid] = sum;
    __syncthreads();
    for (int off = 128; off > 0; off >>= 1) {
        if (tid < off) red[tid] += red[tid + off];
        __syncthreads();
    }
    float inv = 1.0f / red[0];

    int d = tid & (HDIM - 1);
    int half = tid >> 7;
    float acc = 0.f;
    for (int t = half; t <= s_q; t += 2)
        acc += sc[t] * v[(size_t)(t * BATCH + b) * DMODEL + h * HDIM + d];
    obuf[half][d] = acc;
    __syncthreads();
    if (tid < HDIM)
        o[(size_t)tq * DMODEL + h * HDIM + tid] =
            f2bf((obuf[0][tid] + obuf[1][tid]) * inv);
}

// ---------------------------------------------------------------------------
// Launch
// ---------------------------------------------------------------------------
extern "C" void kernel_launch(void* const* d_in, const int* in_sizes, int n_in,
                              void* d_out, int out_size, void* d_ws, size_t ws_size,
                              hipStream_t stream)
{
    const int*   tokens       = (const int*)  d_in[0];
    const float* tok_emb      = (const float*)d_in[1];
    const float* pos_emb      = (const float*)d_in[2];
    const float* attn_norm_w  = (const float*)d_in[3];
    const float* Wq           = (const float*)d_in[4];
    const float* Wk           = (const float*)d_in[5];
    const float* Wv           = (const float*)d_in[6];
    const float* Wo           = (const float*)d_in[7];
    const float* mlp_norm_w   = (const float*)d_in[8];
    const float* W1           = (const float*)d_in[9];
    const float* W2           = (const float*)d_in[10];
    const float* final_norm_w = (const float*)d_in[11];
    float* out = (float*)d_out;

    // ---- workspace layout (~310 MB) ----
    char* wp = (char*)d_ws;
    size_t off = 0;
    auto alloc = [&](size_t bytes) -> void* {
        void* p = wp + off;
        off += (bytes + 255) & ~(size_t)255;
        return p;
    };
    float* x            = (float*)alloc((size_t)NTOK * DMODEL * 4);
    float* qb           = (float*)alloc((size_t)NTOK * DMODEL * 4);
    float* kb           = (float*)alloc((size_t)NTOK * DMODEL * 4);
    float* vb           = (float*)alloc((size_t)NTOK * DMODEL * 4);
    unsigned short* nbf    = (unsigned short*)alloc((size_t)NTOK * DMODEL * 2);
    unsigned short* attnbf = (unsigned short*)alloc((size_t)NTOK * DMODEL * 2);
    unsigned short* hbf    = (unsigned short*)alloc((size_t)NTOK * FFDIM * 2);
    unsigned short* temb   = (unsigned short*)alloc((size_t)VPAD * DMODEL * 2);
    unsigned short* Wq_t   = (unsigned short*)alloc((size_t)NLAYER * DMODEL * DMODEL * 2);
    unsigned short* Wk_t   = (unsigned short*)alloc((size_t)NLAYER * DMODEL * DMODEL * 2);
    unsigned short* Wv_t   = (unsigned short*)alloc((size_t)NLAYER * DMODEL * DMODEL * 2);
    unsigned short* Wo_t   = (unsigned short*)alloc((size_t)NLAYER * DMODEL * DMODEL * 2);
    unsigned short* W1_t   = (unsigned short*)alloc((size_t)NLAYER * DMODEL * FFDIM * 2);
    unsigned short* W2_t   = (unsigned short*)alloc((size_t)NLAYER * FFDIM * DMODEL * 2);
    if (off > ws_size) return;   // workspace too small — bail loudly

    // ---- weight prep ----
    {
        dim3 b(32, 8), g(HDIM / 32, DMODEL / 32, NLAYER * NHEAD);
        transpose_cast_kernel<<<g, b, 0, stream>>>(Wq, Wq_t, DMODEL, HDIM);
        transpose_cast_kernel<<<g, b, 0, stream>>>(Wk, Wk_t, DMODEL, HDIM);
        transpose_cast_kernel<<<g, b, 0, stream>>>(Wv, Wv_t, DMODEL, HDIM);
    }
    {
        dim3 b(32, 8), g(DMODEL / 32, DMODEL / 32, NLAYER);
        transpose_cast_kernel<<<g, b, 0, stream>>>(Wo, Wo_t, DMODEL, DMODEL);
    }
    {
        dim3 b(32, 8), g(FFDIM / 32, DMODEL / 32, NLAYER);
        transpose_cast_kernel<<<g, b, 0, stream>>>(W1, W1_t, DMODEL, FFDIM);
    }
    {
        dim3 b(32, 8), g(DMODEL / 32, FFDIM / 32, NLAYER);
        transpose_cast_kernel<<<g, b, 0, stream>>>(W2, W2_t, FFDIM, DMODEL);
    }
    {
        long n_src = (long)VOCAB * DMODEL, n_tot = (long)VPAD * DMODEL;
        cast_pad_kernel<<<(unsigned)(n_tot / 8 / 256), 256, 0, stream>>>(
            tok_emb, temb, n_src, n_tot);
    }

    // ---- embed ----
    embed_kernel<<<(NTOK * DMODEL) / 256, 256, 0, stream>>>(tokens, tok_emb, pos_emb, x);

    const size_t LW   = (size_t)DMODEL * DMODEL;
    const size_t LWF  = (size_t)DMODEL * FFDIM;

    dim3 g_d(DMODEL / 128, NTOK / 128);    // 8 x 16
    dim3 g_ff(FFDIM / 128, NTOK / 128);    // 32 x 16

    for (int l = 0; l < NLAYER; l++) {
        rmsnorm_bf_kernel<<<NTOK, 256, 0, stream>>>(x, attn_norm_w + (size_t)l * DMODEL, nbf);
        mm_kernel<false, false, false><<<g_d, 256, 0, stream>>>(
            nbf, Wq_t + l * LW, qb, NTOK, DMODEL, DMODEL);
        mm_kernel<false, false, false><<<g_d, 256, 0, stream>>>(
            nbf, Wk_t + l * LW, kb, NTOK, DMODEL, DMODEL);
        mm_kernel<false, false, false><<<g_d, 256, 0, stream>>>(
            nbf, Wv_t + l * LW, vb, NTOK, DMODEL, DMODEL);
        attn_kernel2<<<dim3(SEQ, NHEAD, BATCH), 256, 0, stream>>>(qb, kb, vb, attnbf);
        mm_kernel<true, false, false><<<g_d, 256, 0, stream>>>(
            attnbf, Wo_t + l * LW, x, NTOK, DMODEL, DMODEL);
        rmsnorm_bf_kernel<<<NTOK, 256, 0, stream>>>(x, mlp_norm_w + (size_t)l * DMODEL, nbf);
        mm_kernel<false, true, true><<<g_ff, 256, 0, stream>>>(
            nbf, W1_t + l * LWF, hbf, NTOK, FFDIM, DMODEL);
        mm_kernel<true, false, false><<<g_d, 256, 0, stream>>>(
            hbf, W2_t + l * LWF, x, NTOK, DMODEL, FFDIM);
    }

    rmsnorm_bf_kernel<<<NTOK, 256, 0, stream>>>(x, final_norm_w, nbf);
    dim3 g_v(VPAD / 128, NTOK / 128);      // 393 x 16
    mm_kernel<false, false, false><<<g_v, 256, 0, stream>>>(
        nbf, temb, out, NTOK, VOCAB, DMODEL);
}

// Round 5
// 2537.780 us; speedup vs baseline: 4.9453x; 2.7814x over previous
//
#include <hip/hip_runtime.h>
#include <hip/hip_bf16.h>
#include <cstddef>
#include <cstdint>

// Model dims (fixed by the reference)
#define VOCAB 50257
#define VPAD  50304              // 393 * 128
#define DMODEL 1024
#define NHEAD 8
#define NLAYER 6
#define SEQ 1024
#define BATCH 2
#define HDIM 128
#define FFDIM 4096
#define NTOK (SEQ * BATCH)       // 2048 tokens
#define EPSV 1e-5f

// Token layout is BATCH-MAJOR throughout: token' = b*SEQ + s.
// (Makes each (b,h)'s K/V rows contiguous for attention; the lm-head GEMM
// permutes rows back to (s,b) order on store.)

typedef __attribute__((ext_vector_type(8))) short short8;
typedef __attribute__((ext_vector_type(4))) float f32x4;

__device__ __forceinline__ unsigned short f2bf(float f) {
    union { float f; unsigned u; } v; v.f = f;
    unsigned r = v.u + 0x7FFF + ((v.u >> 16) & 1);   // round-to-nearest-even
    return (unsigned short)(r >> 16);
}

// ---------------------------------------------------------------------------
// Embedding (batch-major): x[b*S+s][d] = tok_emb[tokens[s*B+b]][d] + pos_emb[s][d]
// ---------------------------------------------------------------------------
__global__ __launch_bounds__(256) void embed_kernel(
    const int* __restrict__ tokens, const float* __restrict__ tok_emb,
    const float* __restrict__ pos_emb, float* __restrict__ x)
{
    int idx = blockIdx.x * 256 + threadIdx.x;
    int t = idx >> 10;                    // b*SEQ + s
    int d = idx & (DMODEL - 1);
    int b = t >> 10, s = t & (SEQ - 1);
    int tok = tokens[s * BATCH + b];
    x[idx] = tok_emb[(size_t)tok * DMODEL + d] + pos_emb[(size_t)s * DMODEL + d];
}

// ---------------------------------------------------------------------------
// RMSNorm f32 -> bf16 out. One block per token row (D=1024), float4/thread.
// ---------------------------------------------------------------------------
__global__ __launch_bounds__(256) void rmsnorm_bf_kernel(
    const float* __restrict__ x, const float* __restrict__ w,
    unsigned short* __restrict__ o)
{
    int t = blockIdx.x;
    int tid = threadIdx.x;
    const float4 xv = ((const float4*)(x + (size_t)t * DMODEL))[tid];
    float ss = xv.x * xv.x + xv.y * xv.y + xv.z * xv.z + xv.w * xv.w;
    __shared__ float red[256];
    red[tid] = ss;
    __syncthreads();
    for (int off = 128; off > 0; off >>= 1) {
        if (tid < off) red[tid] += red[tid + off];
        __syncthreads();
    }
    float inv = rsqrtf(red[0] * (1.0f / DMODEL) + EPSV);
    const float4 wv = ((const float4*)w)[tid];
    ushort4 ov;
    ov.x = f2bf(wv.x * xv.x * inv);
    ov.y = f2bf(wv.y * xv.y * inv);
    ov.z = f2bf(wv.z * xv.z * inv);
    ov.w = f2bf(wv.w * xv.w * inv);
    ((ushort4*)(o + (size_t)t * DMODEL))[tid] = ov;
}

// ---------------------------------------------------------------------------
// Batched transpose + f32->bf16 cast: in [batch][R][C] f32 -> out [batch][C][R] bf16
// ---------------------------------------------------------------------------
__global__ __launch_bounds__(256) void transpose_cast_kernel(
    const float* __restrict__ in, unsigned short* __restrict__ out, int R, int C)
{
    __shared__ float tile[32][33];
    const size_t bo = (size_t)blockIdx.z * R * C;
    const float* src = in + bo;
    unsigned short* dst = out + bo;
    int c0 = blockIdx.x * 32, r0 = blockIdx.y * 32;
    int tx = threadIdx.x, ty = threadIdx.y;
    #pragma unroll
    for (int i = 0; i < 32; i += 8)
        tile[ty + i][tx] = src[(size_t)(r0 + ty + i) * C + c0 + tx];
    __syncthreads();
    #pragma unroll
    for (int i = 0; i < 32; i += 8)
        dst[(size_t)(c0 + ty + i) * R + r0 + tx] = f2bf(tile[tx][ty + i]);
}

// ---------------------------------------------------------------------------
// f32 -> bf16 flat cast with zero padding (tok_emb -> [VPAD][D] bf16)
// ---------------------------------------------------------------------------
__global__ __launch_bounds__(256) void cast_pad_kernel(
    const float* __restrict__ in, unsigned short* __restrict__ out,
    long n_src, long n_tot)
{
    long i = ((long)blockIdx.x * 256 + threadIdx.x) * 8;
    if (i >= n_tot) return;
    short8 o8;
    if (i < n_src) {
        const float4* p = (const float4*)(in + i);
        float4 a = p[0], b = p[1];
        o8[0] = (short)f2bf(a.x); o8[1] = (short)f2bf(a.y);
        o8[2] = (short)f2bf(a.z); o8[3] = (short)f2bf(a.w);
        o8[4] = (short)f2bf(b.x); o8[5] = (short)f2bf(b.y);
        o8[6] = (short)f2bf(b.z); o8[7] = (short)f2bf(b.w);
    } else {
        o8 = (short8)0;
    }
    *(short8*)(out + i) = o8;
}

// ---------------------------------------------------------------------------
// bf16 MFMA GEMM (m97 structure): C[M][N] = A[M][K] * Bt[N][K]^T
// 128x128 tile, BK=32, 256 threads. RM: 0 = direct row, 1 = permute output
// row b*S+s -> s*B+b (lm-head).
// ---------------------------------------------------------------------------
template<bool ACC, bool SILU, bool BF16OUT, int RM>
__global__ __launch_bounds__(256) void mm_kernel(
    const unsigned short* __restrict__ A, const unsigned short* __restrict__ Bt,
    void* __restrict__ Cv, int M, int N, int K)
{
    __shared__ unsigned short lds[8192];   // A: elems [0,4096), B: [4096,8192)
    const int tid  = threadIdx.x;
    const int lane = tid & 63;
    const int wave = tid >> 6;
    const int wm = wave >> 1, wn = wave & 1;
    const int row0 = blockIdx.y * 128;
    const int col0 = blockIdx.x * 128;

    f32x4 acc[4][4] = {};

    const int off_base = wave * 4096 + lane * 16;  // byte offset in combined 16KB region
    const int kfr = (lane >> 4) * 8;
    const int l15 = lane & 15;

    for (int k0 = 0; k0 < K; k0 += 32) {
        #pragma unroll
        for (int c = 0; c < 4; ++c) {
            int off  = off_base + c * 1024;
            int row  = (off & 8191) >> 6;
            int koff = (off >> 1) & 31;
            const unsigned short* src = (off < 8192)
                ? A  + (size_t)(row0 + row) * K + k0 + koff
                : Bt + (size_t)(col0 + row) * K + k0 + koff;
            unsigned short* dst = lds + ((wave * 4096 + c * 1024) >> 1);
            __builtin_amdgcn_global_load_lds(
                (const __attribute__((address_space(1))) void*)src,
                (__attribute__((address_space(3))) void*)dst, 16, 0, 0);
        }
        __syncthreads();

        short8 af[4], bfr[4];
        #pragma unroll
        for (int i = 0; i < 4; ++i)
            af[i] = *(const short8*)&lds[(wm * 64 + i * 16 + l15) * 32 + kfr];
        #pragma unroll
        for (int j = 0; j < 4; ++j)
            bfr[j] = *(const short8*)&lds[4096 + (wn * 64 + j * 16 + l15) * 32 + kfr];
        #pragma unroll
        for (int i = 0; i < 4; ++i)
            #pragma unroll
            for (int j = 0; j < 4; ++j)
                acc[i][j] = __builtin_amdgcn_mfma_f32_16x16x32_bf16(
                    af[i], bfr[j], acc[i][j], 0, 0, 0);
        __syncthreads();
    }

    float* Cf = (float*)Cv;
    unsigned short* Cb = (unsigned short*)Cv;
    const int crow  = row0 + wm * 64 + ((lane >> 4) << 2);
    const int ccol0 = col0 + wn * 64 + l15;
    #pragma unroll
    for (int i = 0; i < 4; ++i) {
        #pragma unroll
        for (int j = 0; j < 4; ++j) {
            int gcol = ccol0 + j * 16;
            if (gcol < N) {
                #pragma unroll
                for (int r = 0; r < 4; ++r) {
                    int grow = crow + i * 16 + r;
                    int orow = RM ? (((grow & (SEQ - 1)) << 1) | (grow >> 10)) : grow;
                    float v = acc[i][j][r];
                    if (SILU) v = v / (1.0f + __expf(-v));
                    size_t ci = (size_t)orow * N + gcol;
                    if (BF16OUT)      Cb[ci] = f2bf(v);
                    else if (ACC)     Cf[ci] += v;
                    else              Cf[ci] = v;
                }
            }
        }
    }
}

// ---------------------------------------------------------------------------
// Flash attention (bf16 MFMA). Grid (S/64, H, B); 4 waves/block, wave = 16
// q-rows. KVBLK=64 staged in LDS (XOR-swizzled). Swapped QK^T (S^T = K·Q^T)
// keeps per-q softmax state lane-local (q = lane&15); PV computed as
// O^T = Vt·P so state stays lane-local. P goes through a wave-private LDS
// buffer to reach MFMA B-fragment layout.
// q,k: bf16 [token'][h*128+d]; vt: bf16 [h*128+d][token']; o: bf16 [token'][h*128+d]
// ---------------------------------------------------------------------------
__global__ __launch_bounds__(256) void flash_attn_kernel(
    const unsigned short* __restrict__ q, const unsigned short* __restrict__ k,
    const unsigned short* __restrict__ vt, unsigned short* __restrict__ o)
{
    const int qt   = blockIdx.x;          // q-tile (64 rows)
    const int h    = blockIdx.y;
    const int b    = blockIdx.z;
    const int tid  = threadIdx.x;
    const int lane = tid & 63;
    const int wave = tid >> 6;
    const int g    = lane >> 4;           // lane group 0..3
    const int c    = lane & 15;

    __shared__ unsigned short k_lds[64 * 128];    // [key][d], swizzled; 16KB
    __shared__ unsigned short vt_lds[128 * 64];   // [d][key], swizzled; 16KB
    __shared__ unsigned short p_lds[4 * 16 * 64]; // per-wave [q][key], swizzled; 8KB

    const int q0  = qt * 64;
    const int wq0 = q0 + wave * 16;
    const int tokb = b * SEQ;

    // Q fragments (B operand): row q = wq0+c, d = dblk*32 + g*8 .. +7
    short8 qf[4];
    {
        const unsigned short* qr =
            q + (size_t)(tokb + wq0 + c) * DMODEL + h * HDIM + g * 8;
        #pragma unroll
        for (int dblk = 0; dblk < 4; ++dblk)
            qf[dblk] = *(const short8*)(qr + dblk * 32);
    }

    f32x4 oacc[8] = {};
    float m = -1e30f, l = 0.f;
    const float scale = 0.08838834764831845f;     // 1/sqrt(128)
    const int myq = wq0 + c;

    const int nt = qt + 1;
    for (int it = 0; it < nt; ++it) {
        const int kv0 = it * 64;
        // global loads (before barrier — no LDS dependence)
        // K tile: 64 keys x 128 d x 2B = 16KB = 1024 chunks of 16B; 16 chunks/row
        short8 kc[4], vc[4];
        #pragma unroll
        for (int i = 0; i < 4; ++i) {
            int chunk = tid + i * 256;
            int key = chunk >> 4, cc = chunk & 15;
            kc[i] = *(const short8*)(
                k + (size_t)(tokb + kv0 + key) * DMODEL + h * HDIM + cc * 8);
        }
        // Vt tile: 128 d-rows x 64 keys x 2B = 16KB; 8 chunks/row
        #pragma unroll
        for (int i = 0; i < 4; ++i) {
            int chunk = tid + i * 256;
            int d = chunk >> 3, cc = chunk & 7;
            vc[i] = *(const short8*)(
                vt + (size_t)(h * HDIM + d) * NTOK + tokb + kv0 + cc * 8);
        }
        __syncthreads();   // prior iteration's LDS reads done
        #pragma unroll
        for (int i = 0; i < 4; ++i) {
            int chunk = tid + i * 256;
            int key = chunk >> 4, cc = chunk & 15;
            *(short8*)((char*)k_lds + ((key * 256 + cc * 16) ^ ((key & 7) << 4))) = kc[i];
        }
        #pragma unroll
        for (int i = 0; i < 4; ++i) {
            int chunk = tid + i * 256;
            int d = chunk >> 3, cc = chunk & 7;
            *(short8*)((char*)vt_lds + ((d * 128 + cc * 16) ^ ((d & 7) << 4))) = vc[i];
        }
        __syncthreads();

        // S^T tiles: st[sub] covers keys kv0+sub*16.. ; lane: col q=c, rows key
        f32x4 st[4];
        #pragma unroll
        for (int sub = 0; sub < 4; ++sub) {
            f32x4 acc = {};
            int key = sub * 16 + c;
            #pragma unroll
            for (int dblk = 0; dblk < 4; ++dblk) {
                short8 kf = *(const short8*)((char*)k_lds +
                    ((key * 256 + dblk * 64 + g * 16) ^ ((key & 7) << 4)));
                acc = __builtin_amdgcn_mfma_f32_16x16x32_bf16(kf, qf[dblk], acc, 0, 0, 0);
            }
            st[sub] = acc;
        }

        // scale + causal mask
        #pragma unroll
        for (int sub = 0; sub < 4; ++sub)
            #pragma unroll
            for (int r = 0; r < 4; ++r) {
                int key = kv0 + sub * 16 + g * 4 + r;
                float s = st[sub][r] * scale;
                st[sub][r] = (key <= myq) ? s : -1e30f;
            }

        // online softmax (state per q = lane&15)
        float tm = -1e30f;
        #pragma unroll
        for (int sub = 0; sub < 4; ++sub)
            #pragma unroll
            for (int r = 0; r < 4; ++r) tm = fmaxf(tm, st[sub][r]);
        tm = fmaxf(tm, __shfl_xor(tm, 16));
        tm = fmaxf(tm, __shfl_xor(tm, 32));
        float mnew = fmaxf(m, tm);
        float sc_f = __expf(m - mnew);
        m = mnew;

        float ps = 0.f;
        #pragma unroll
        for (int sub = 0; sub < 4; ++sub) {
            float p0 = __expf(st[sub][0] - m);
            float p1 = __expf(st[sub][1] - m);
            float p2 = __expf(st[sub][2] - m);
            float p3 = __expf(st[sub][3] - m);
            ps += (p0 + p1) + (p2 + p3);
            ushort4 pk;
            pk.x = f2bf(p0); pk.y = f2bf(p1); pk.z = f2bf(p2); pk.w = f2bf(p3);
            // P[q=c][key=sub*16+g*4 .. +3]
            *(ushort4*)((char*)p_lds + wave * 2048 +
                ((c * 128 + sub * 32 + g * 8) ^ ((c & 7) << 4))) = pk;
        }
        ps += __shfl_xor(ps, 16);
        ps += __shfl_xor(ps, 32);
        l = l * sc_f + ps;
        #pragma unroll
        for (int dt = 0; dt < 8; ++dt)
            #pragma unroll
            for (int r = 0; r < 4; ++r) oacc[dt][r] *= sc_f;

        // PV: O^T[d][q] += Vt[d][k] * P[k][q]
        #pragma unroll
        for (int kb = 0; kb < 2; ++kb) {
            short8 pf = *(const short8*)((char*)p_lds + wave * 2048 +
                ((c * 128 + kb * 64 + g * 16) ^ ((c & 7) << 4)));
            #pragma unroll
            for (int dt = 0; dt < 8; ++dt) {
                int d = dt * 16 + c;
                short8 vf = *(const short8*)((char*)vt_lds +
                    ((d * 128 + kb * 64 + g * 16) ^ ((d & 7) << 4)));
                oacc[dt] = __builtin_amdgcn_mfma_f32_16x16x32_bf16(vf, pf, oacc[dt], 0, 0, 0);
            }
        }
    }

    // epilogue: lane holds O^T rows d=dt*16+g*4+r for col q=c
    float inv = 1.0f / l;
    unsigned short* orow = o + (size_t)(tokb + wq0 + c) * DMODEL + h * HDIM + g * 4;
    #pragma unroll
    for (int dt = 0; dt < 8; ++dt) {
        ushort4 ov;
        ov.x = f2bf(oacc[dt][0] * inv);
        ov.y = f2bf(oacc[dt][1] * inv);
        ov.z = f2bf(oacc[dt][2] * inv);
        ov.w = f2bf(oacc[dt][3] * inv);
        *(ushort4*)(orow + dt * 16) = ov;
    }
}

// ---------------------------------------------------------------------------
// Launch
// ---------------------------------------------------------------------------
extern "C" void kernel_launch(void* const* d_in, const int* in_sizes, int n_in,
                              void* d_out, int out_size, void* d_ws, size_t ws_size,
                              hipStream_t stream)
{
    const int*   tokens       = (const int*)  d_in[0];
    const float* tok_emb      = (const float*)d_in[1];
    const float* pos_emb      = (const float*)d_in[2];
    const float* attn_norm_w  = (const float*)d_in[3];
    const float* Wq           = (const float*)d_in[4];
    const float* Wk           = (const float*)d_in[5];
    const float* Wv           = (const float*)d_in[6];
    const float* Wo           = (const float*)d_in[7];
    const float* mlp_norm_w   = (const float*)d_in[8];
    const float* W1           = (const float*)d_in[9];
    const float* W2           = (const float*)d_in[10];
    const float* final_norm_w = (const float*)d_in[11];
    float* out = (float*)d_out;

    // ---- workspace layout (~350 MB) ----
    char* wp = (char*)d_ws;
    size_t off = 0;
    auto alloc = [&](size_t bytes) -> void* {
        void* p = wp + off;
        off += (bytes + 255) & ~(size_t)255;
        return p;
    };
    float* x            = (float*)alloc((size_t)NTOK * DMODEL * 4);
    unsigned short* nbf    = (unsigned short*)alloc((size_t)NTOK * DMODEL * 2);
    unsigned short* qbf    = (unsigned short*)alloc((size_t)NTOK * DMODEL * 2);
    unsigned short* kbf    = (unsigned short*)alloc((size_t)NTOK * DMODEL * 2);
    unsigned short* vtb    = (unsigned short*)alloc((size_t)DMODEL * NTOK * 2);
    unsigned short* attnbf = (unsigned short*)alloc((size_t)NTOK * DMODEL * 2);
    unsigned short* hbf    = (unsigned short*)alloc((size_t)NTOK * FFDIM * 2);
    unsigned short* temb   = (unsigned short*)alloc((size_t)VPAD * DMODEL * 2);
    unsigned short* Wq_t   = (unsigned short*)alloc((size_t)NLAYER * DMODEL * DMODEL * 2);
    unsigned short* Wk_t   = (unsigned short*)alloc((size_t)NLAYER * DMODEL * DMODEL * 2);
    unsigned short* Wv_t   = (unsigned short*)alloc((size_t)NLAYER * DMODEL * DMODEL * 2);
    unsigned short* Wo_t   = (unsigned short*)alloc((size_t)NLAYER * DMODEL * DMODEL * 2);
    unsigned short* W1_t   = (unsigned short*)alloc((size_t)NLAYER * DMODEL * FFDIM * 2);
    unsigned short* W2_t   = (unsigned short*)alloc((size_t)NLAYER * FFDIM * DMODEL * 2);
    if (off > ws_size) return;

    // ---- weight prep ----
    {
        dim3 bb(32, 8), g(HDIM / 32, DMODEL / 32, NLAYER * NHEAD);
        transpose_cast_kernel<<<g, bb, 0, stream>>>(Wq, Wq_t, DMODEL, HDIM);
        transpose_cast_kernel<<<g, bb, 0, stream>>>(Wk, Wk_t, DMODEL, HDIM);
        transpose_cast_kernel<<<g, bb, 0, stream>>>(Wv, Wv_t, DMODEL, HDIM);
    }
    {
        dim3 bb(32, 8), g(DMODEL / 32, DMODEL / 32, NLAYER);
        transpose_cast_kernel<<<g, bb, 0, stream>>>(Wo, Wo_t, DMODEL, DMODEL);
    }
    {
        dim3 bb(32, 8), g(FFDIM / 32, DMODEL / 32, NLAYER);
        transpose_cast_kernel<<<g, bb, 0, stream>>>(W1, W1_t, DMODEL, FFDIM);
    }
    {
        dim3 bb(32, 8), g(DMODEL / 32, FFDIM / 32, NLAYER);
        transpose_cast_kernel<<<g, bb, 0, stream>>>(W2, W2_t, FFDIM, DMODEL);
    }
    {
        long n_src = (long)VOCAB * DMODEL, n_tot = (long)VPAD * DMODEL;
        cast_pad_kernel<<<(unsigned)(n_tot / 8 / 256), 256, 0, stream>>>(
            tok_emb, temb, n_src, n_tot);
    }

    // ---- embed ----
    embed_kernel<<<(NTOK * DMODEL) / 256, 256, 0, stream>>>(tokens, tok_emb, pos_emb, x);

    const size_t LW  = (size_t)DMODEL * DMODEL;
    const size_t LWF = (size_t)DMODEL * FFDIM;

    dim3 g_d(DMODEL / 128, NTOK / 128);    // 8 x 16
    dim3 g_vt(NTOK / 128, DMODEL / 128);   // 16 x 8  (vt GEMM: M=1024, N=2048)
    dim3 g_ff(FFDIM / 128, NTOK / 128);    // 32 x 16

    for (int l = 0; l < NLAYER; l++) {
        rmsnorm_bf_kernel<<<NTOK, 256, 0, stream>>>(x, attn_norm_w + (size_t)l * DMODEL, nbf);
        mm_kernel<false, false, true, 0><<<g_d, 256, 0, stream>>>(
            nbf, Wq_t + l * LW, qbf, NTOK, DMODEL, DMODEL);
        mm_kernel<false, false, true, 0><<<g_d, 256, 0, stream>>>(
            nbf, Wk_t + l * LW, kbf, NTOK, DMODEL, DMODEL);
        // Vt[hd][token] = Wv_t[hd][:] . n[token][:]   (swapped-role GEMM)
        mm_kernel<false, false, true, 0><<<g_vt, 256, 0, stream>>>(
            Wv_t + l * LW, nbf, vtb, DMODEL, NTOK, DMODEL);
        flash_attn_kernel<<<dim3(SEQ / 64, NHEAD, BATCH), 256, 0, stream>>>(
            qbf, kbf, vtb, attnbf);
        mm_kernel<true, false, false, 0><<<g_d, 256, 0, stream>>>(
            attnbf, Wo_t + l * LW, x, NTOK, DMODEL, DMODEL);
        rmsnorm_bf_kernel<<<NTOK, 256, 0, stream>>>(x, mlp_norm_w + (size_t)l * DMODEL, nbf);
        mm_kernel<false, true, true, 0><<<g_ff, 256, 0, stream>>>(
            nbf, W1_t + l * LWF, hbf, NTOK, FFDIM, DMODEL);
        mm_kernel<true, false, false, 0><<<g_d, 256, 0, stream>>>(
            hbf, W2_t + l * LWF, x, NTOK, DMODEL, FFDIM);
    }

    rmsnorm_bf_kernel<<<NTOK, 256, 0, stream>>>(x, final_norm_w, nbf);
    dim3 g_v(VPAD / 128, NTOK / 128);      // 393 x 16
    mm_kernel<false, false, false, 1><<<g_v, 256, 0, stream>>>(
        nbf, temb, out, NTOK, VOCAB, DMODEL);
}

// Round 6
// 2459.441 us; speedup vs baseline: 5.1029x; 1.0319x over previous
//
#include <hip/hip_runtime.h>
#include <hip/hip_bf16.h>
#include <cstddef>
#include <cstdint>

// Model dims (fixed by the reference)
#define VOCAB 50257
#define VPAD  50304              // 393 * 128
#define DMODEL 1024
#define NHEAD 8
#define NLAYER 6
#define SEQ 1024
#define BATCH 2
#define HDIM 128
#define FFDIM 4096
#define NTOK (SEQ * BATCH)       // 2048 tokens
#define QKLD 2048                // q/k combined row stride
#define EPSV 1e-5f

// Token layout is BATCH-MAJOR throughout: token' = b*SEQ + s.

typedef __attribute__((ext_vector_type(8))) short short8;
typedef __attribute__((ext_vector_type(4))) float f32x4;

__device__ __forceinline__ unsigned short f2bf(float f) {
    union { float f; unsigned u; } v; v.f = f;
    unsigned r = v.u + 0x7FFF + ((v.u >> 16) & 1);   // round-to-nearest-even
    return (unsigned short)(r >> 16);
}

// ---------------------------------------------------------------------------
// Embedding (batch-major)
// ---------------------------------------------------------------------------
__global__ __launch_bounds__(256) void embed_kernel(
    const int* __restrict__ tokens, const float* __restrict__ tok_emb,
    const float* __restrict__ pos_emb, float* __restrict__ x)
{
    int idx = blockIdx.x * 256 + threadIdx.x;
    int t = idx >> 10;                    // b*SEQ + s
    int d = idx & (DMODEL - 1);
    int b = t >> 10, s = t & (SEQ - 1);
    int tok = tokens[s * BATCH + b];
    x[idx] = tok_emb[(size_t)tok * DMODEL + d] + pos_emb[(size_t)s * DMODEL + d];
}

// ---------------------------------------------------------------------------
// RMSNorm f32 -> bf16
// ---------------------------------------------------------------------------
__global__ __launch_bounds__(256) void rmsnorm_bf_kernel(
    const float* __restrict__ x, const float* __restrict__ w,
    unsigned short* __restrict__ o)
{
    int t = blockIdx.x;
    int tid = threadIdx.x;
    const float4 xv = ((const float4*)(x + (size_t)t * DMODEL))[tid];
    float ss = xv.x * xv.x + xv.y * xv.y + xv.z * xv.z + xv.w * xv.w;
    __shared__ float red[256];
    red[tid] = ss;
    __syncthreads();
    for (int off = 128; off > 0; off >>= 1) {
        if (tid < off) red[tid] += red[tid + off];
        __syncthreads();
    }
    float inv = rsqrtf(red[0] * (1.0f / DMODEL) + EPSV);
    const float4 wv = ((const float4*)w)[tid];
    ushort4 ov;
    ov.x = f2bf(wv.x * xv.x * inv);
    ov.y = f2bf(wv.y * xv.y * inv);
    ov.z = f2bf(wv.z * xv.z * inv);
    ov.w = f2bf(wv.w * xv.w * inv);
    ((ushort4*)(o + (size_t)t * DMODEL))[tid] = ov;
}

// ---------------------------------------------------------------------------
// Batched transpose + cast: in [z][R][C] f32 -> out [z][C][R] bf16
// ---------------------------------------------------------------------------
__global__ __launch_bounds__(256) void transpose_cast_kernel(
    const float* __restrict__ in, unsigned short* __restrict__ out, int R, int C)
{
    __shared__ float tile[32][33];
    const size_t bo = (size_t)blockIdx.z * R * C;
    const float* src = in + bo;
    unsigned short* dst = out + bo;
    int c0 = blockIdx.x * 32, r0 = blockIdx.y * 32;
    int tx = threadIdx.x, ty = threadIdx.y;
    #pragma unroll
    for (int i = 0; i < 32; i += 8)
        tile[ty + i][tx] = src[(size_t)(r0 + ty + i) * C + c0 + tx];
    __syncthreads();
    #pragma unroll
    for (int i = 0; i < 32; i += 8)
        dst[(size_t)(c0 + ty + i) * R + r0 + tx] = f2bf(tile[tx][ty + i]);
}

// ---------------------------------------------------------------------------
// Q/K weight transpose into combined Wqk_t [l][2048][1024] at row offset.
// in: [l*H][1024][128] f32. grid (4, 32, L*H), block (32,8).
// ---------------------------------------------------------------------------
__global__ __launch_bounds__(256) void transpose_qkv_kernel(
    const float* __restrict__ in, unsigned short* __restrict__ out, int row_off)
{
    __shared__ float tile[32][33];
    int z = blockIdx.z;
    int l = z >> 3, h = z & 7;
    const float* src = in + (size_t)z * DMODEL * HDIM;
    unsigned short* dst = out + (size_t)l * QKLD * DMODEL
                              + (size_t)(row_off + h * HDIM) * DMODEL;
    int c0 = blockIdx.x * 32, r0 = blockIdx.y * 32;
    int tx = threadIdx.x, ty = threadIdx.y;
    #pragma unroll
    for (int i = 0; i < 32; i += 8)
        tile[ty + i][tx] = src[(size_t)(r0 + ty + i) * HDIM + c0 + tx];
    __syncthreads();
    #pragma unroll
    for (int i = 0; i < 32; i += 8)
        dst[(size_t)(c0 + ty + i) * DMODEL + r0 + tx] = f2bf(tile[tx][ty + i]);
}

// ---------------------------------------------------------------------------
// f32 -> bf16 flat cast with zero padding
// ---------------------------------------------------------------------------
__global__ __launch_bounds__(256) void cast_pad_kernel(
    const float* __restrict__ in, unsigned short* __restrict__ out,
    long n_src, long n_tot)
{
    long i = ((long)blockIdx.x * 256 + threadIdx.x) * 8;
    if (i >= n_tot) return;
    short8 o8;
    if (i < n_src) {
        const float4* p = (const float4*)(in + i);
        float4 a = p[0], b = p[1];
        o8[0] = (short)f2bf(a.x); o8[1] = (short)f2bf(a.y);
        o8[2] = (short)f2bf(a.z); o8[3] = (short)f2bf(a.w);
        o8[4] = (short)f2bf(b.x); o8[5] = (short)f2bf(b.y);
        o8[6] = (short)f2bf(b.z); o8[7] = (short)f2bf(b.w);
    } else {
        o8 = (short8)0;
    }
    *(short8*)(out + i) = o8;
}

// ---------------------------------------------------------------------------
// bf16 MFMA GEMM (m97 structure): C[M][N] = A[M][K] * Bt[N][K]^T
// 128x128 tile, BK=32, 256 threads, 1D grid. Block order: col-major within
// bijective XCD chunks (consecutive blocks share the B-panel -> L2 reuse;
// each XCD streams a distinct column range of B once from HBM).
// rows = M/128 passed by host; cols = gridDim.x / rows.
// ---------------------------------------------------------------------------
template<bool ACC, bool SILU, bool BF16OUT, int RM>
__global__ __launch_bounds__(256) void mm_kernel(
    const unsigned short* __restrict__ A, const unsigned short* __restrict__ Bt,
    void* __restrict__ Cv, int M, int N, int K, int rows)
{
    // ---- bijective XCD swizzle (m204), then col-major decomposition ----
    int nwg = gridDim.x;
    int flat = blockIdx.x;
    int q8 = nwg >> 3, r8 = nwg & 7;
    int xcd = flat & 7, lid = flat >> 3;
    int wg = (r8 == 0) ? (xcd * q8 + lid)
           : ((xcd < r8 ? xcd * (q8 + 1) : r8 * (q8 + 1) + (xcd - r8) * q8) + lid);
    const int row0 = (wg % rows) * 128;
    const int col0 = (wg / rows) * 128;

    __shared__ unsigned short lds[8192];   // A: elems [0,4096), B: [4096,8192)
    const int tid  = threadIdx.x;
    const int lane = tid & 63;
    const int wave = tid >> 6;
    const int wm = wave >> 1, wn = wave & 1;

    f32x4 acc[4][4] = {};

    const int off_base = wave * 4096 + lane * 16;  // byte offset in 16KB region
    const int kfr = (lane >> 4) * 8;
    const int l15 = lane & 15;

    for (int k0 = 0; k0 < K; k0 += 32) {
        #pragma unroll
        for (int c = 0; c < 4; ++c) {
            int off  = off_base + c * 1024;
            int row  = (off & 8191) >> 6;
            int koff = (off >> 1) & 31;
            const unsigned short* src = (off < 8192)
                ? A  + (size_t)(row0 + row) * K + k0 + koff
                : Bt + (size_t)(col0 + row) * K + k0 + koff;
            unsigned short* dst = lds + ((wave * 4096 + c * 1024) >> 1);
            __builtin_amdgcn_global_load_lds(
                (const __attribute__((address_space(1))) void*)src,
                (__attribute__((address_space(3))) void*)dst, 16, 0, 0);
        }
        __syncthreads();

        short8 af[4], bfr[4];
        #pragma unroll
        for (int i = 0; i < 4; ++i)
            af[i] = *(const short8*)&lds[(wm * 64 + i * 16 + l15) * 32 + kfr];
        #pragma unroll
        for (int j = 0; j < 4; ++j)
            bfr[j] = *(const short8*)&lds[4096 + (wn * 64 + j * 16 + l15) * 32 + kfr];
        #pragma unroll
        for (int i = 0; i < 4; ++i)
            #pragma unroll
            for (int j = 0; j < 4; ++j)
                acc[i][j] = __builtin_amdgcn_mfma_f32_16x16x32_bf16(
                    af[i], bfr[j], acc[i][j], 0, 0, 0);
        __syncthreads();
    }

    float* Cf = (float*)Cv;
    unsigned short* Cb = (unsigned short*)Cv;
    const int crow  = row0 + wm * 64 + ((lane >> 4) << 2);
    const int ccol0 = col0 + wn * 64 + l15;
    #pragma unroll
    for (int i = 0; i < 4; ++i) {
        #pragma unroll
        for (int j = 0; j < 4; ++j) {
            int gcol = ccol0 + j * 16;
            if (gcol < N) {
                #pragma unroll
                for (int r = 0; r < 4; ++r) {
                    int grow = crow + i * 16 + r;
                    int orow = RM ? (((grow & (SEQ - 1)) << 1) | (grow >> 10)) : grow;
                    float v = acc[i][j][r];
                    if (SILU) v = v / (1.0f + __expf(-v));
                    size_t ci = (size_t)orow * N + gcol;
                    if (BF16OUT)      Cb[ci] = f2bf(v);
                    else if (ACC)     Cf[ci] += v;
                    else              Cf[ci] = v;
                }
            }
        }
    }
}

// ---------------------------------------------------------------------------
// Flash attention (bf16 MFMA). Grid (S/64, H, B); 4 waves/block, wave = 16
// q-rows. KVBLK=64 in LDS (XOR-swizzled). Swapped QK^T keeps softmax state
// lane-local (q = lane&15); PV = Vt*P keeps O^T state lane-local.
// q,k: bf16 [token'][QKLD] (k base already offset); vt: bf16 [hd][token'].
// ---------------------------------------------------------------------------
__global__ __launch_bounds__(256) void flash_attn_kernel(
    const unsigned short* __restrict__ q, const unsigned short* __restrict__ k,
    const unsigned short* __restrict__ vt, unsigned short* __restrict__ o)
{
    const int qt   = blockIdx.x;          // q-tile (64 rows)
    const int h    = blockIdx.y;
    const int b    = blockIdx.z;
    const int tid  = threadIdx.x;
    const int lane = tid & 63;
    const int wave = tid >> 6;
    const int g    = lane >> 4;           // lane group 0..3
    const int c    = lane & 15;

    __shared__ unsigned short k_lds[64 * 128];    // [key][d], swizzled; 16KB
    __shared__ unsigned short vt_lds[128 * 64];   // [d][key], swizzled; 16KB
    __shared__ unsigned short p_lds[4 * 16 * 64]; // per-wave [q][key]; 8KB

    const int q0  = qt * 64;
    const int wq0 = q0 + wave * 16;
    const int tokb = b * SEQ;

    // Q fragments (B operand): row q = wq0+c, d = dblk*32 + g*8 .. +7
    short8 qf[4];
    {
        const unsigned short* qr =
            q + (size_t)(tokb + wq0 + c) * QKLD + h * HDIM + g * 8;
        #pragma unroll
        for (int dblk = 0; dblk < 4; ++dblk)
            qf[dblk] = *(const short8*)(qr + dblk * 32);
    }

    f32x4 oacc[8] = {};
    float m = -1e30f, l = 0.f;
    const float scale = 0.08838834764831845f;     // 1/sqrt(128)
    const int myq = wq0 + c;

    const int nt = qt + 1;
    for (int it = 0; it < nt; ++it) {
        const int kv0 = it * 64;
        // K tile: 64 keys x 128 d = 1024 chunks of 16B; 16 chunks/row
        short8 kc[4], vc[4];
        #pragma unroll
        for (int i = 0; i < 4; ++i) {
            int chunk = tid + i * 256;
            int key = chunk >> 4, cc = chunk & 15;
            kc[i] = *(const short8*)(
                k + (size_t)(tokb + kv0 + key) * QKLD + h * HDIM + cc * 8);
        }
        // Vt tile: 128 d-rows x 64 keys; 8 chunks/row
        #pragma unroll
        for (int i = 0; i < 4; ++i) {
            int chunk = tid + i * 256;
            int d = chunk >> 3, cc = chunk & 7;
            vc[i] = *(const short8*)(
                vt + (size_t)(h * HDIM + d) * NTOK + tokb + kv0 + cc * 8);
        }
        __syncthreads();   // prior iteration's LDS reads done
        #pragma unroll
        for (int i = 0; i < 4; ++i) {
            int chunk = tid + i * 256;
            int key = chunk >> 4, cc = chunk & 15;
            *(short8*)((char*)k_lds + ((key * 256 + cc * 16) ^ ((key & 7) << 4))) = kc[i];
        }
        #pragma unroll
        for (int i = 0; i < 4; ++i) {
            int chunk = tid + i * 256;
            int d = chunk >> 3, cc = chunk & 7;
            *(short8*)((char*)vt_lds + ((d * 128 + cc * 16) ^ ((d & 7) << 4))) = vc[i];
        }
        __syncthreads();

        // S^T tiles
        f32x4 st[4];
        #pragma unroll
        for (int sub = 0; sub < 4; ++sub) {
            f32x4 acc = {};
            int key = sub * 16 + c;
            #pragma unroll
            for (int dblk = 0; dblk < 4; ++dblk) {
                short8 kf = *(const short8*)((char*)k_lds +
                    ((key * 256 + dblk * 64 + g * 16) ^ ((key & 7) << 4)));
                acc = __builtin_amdgcn_mfma_f32_16x16x32_bf16(kf, qf[dblk], acc, 0, 0, 0);
            }
            st[sub] = acc;
        }

        // scale + causal mask
        #pragma unroll
        for (int sub = 0; sub < 4; ++sub)
            #pragma unroll
            for (int r = 0; r < 4; ++r) {
                int key = kv0 + sub * 16 + g * 4 + r;
                float s = st[sub][r] * scale;
                st[sub][r] = (key <= myq) ? s : -1e30f;
            }

        // online softmax (state per q = lane&15)
        float tm = -1e30f;
        #pragma unroll
        for (int sub = 0; sub < 4; ++sub)
            #pragma unroll
            for (int r = 0; r < 4; ++r) tm = fmaxf(tm, st[sub][r]);
        tm = fmaxf(tm, __shfl_xor(tm, 16));
        tm = fmaxf(tm, __shfl_xor(tm, 32));
        float mnew = fmaxf(m, tm);
        float sc_f = __expf(m - mnew);
        m = mnew;

        float ps = 0.f;
        #pragma unroll
        for (int sub = 0; sub < 4; ++sub) {
            float p0 = __expf(st[sub][0] - m);
            float p1 = __expf(st[sub][1] - m);
            float p2 = __expf(st[sub][2] - m);
            float p3 = __expf(st[sub][3] - m);
            ps += (p0 + p1) + (p2 + p3);
            ushort4 pk;
            pk.x = f2bf(p0); pk.y = f2bf(p1); pk.z = f2bf(p2); pk.w = f2bf(p3);
            *(ushort4*)((char*)p_lds + wave * 2048 +
                ((c * 128 + sub * 32 + g * 8) ^ ((c & 7) << 4))) = pk;
        }
        ps += __shfl_xor(ps, 16);
        ps += __shfl_xor(ps, 32);
        l = l * sc_f + ps;
        #pragma unroll
        for (int dt = 0; dt < 8; ++dt)
            #pragma unroll
            for (int r = 0; r < 4; ++r) oacc[dt][r] *= sc_f;

        // PV: O^T[d][q] += Vt[d][k] * P[k][q]
        #pragma unroll
        for (int kb = 0; kb < 2; ++kb) {
            short8 pf = *(const short8*)((char*)p_lds + wave * 2048 +
                ((c * 128 + kb * 64 + g * 16) ^ ((c & 7) << 4)));
            #pragma unroll
            for (int dt = 0; dt < 8; ++dt) {
                int d = dt * 16 + c;
                short8 vf = *(const short8*)((char*)vt_lds +
                    ((d * 128 + kb * 64 + g * 16) ^ ((d & 7) << 4)));
                oacc[dt] = __builtin_amdgcn_mfma_f32_16x16x32_bf16(vf, pf, oacc[dt], 0, 0, 0);
            }
        }
    }

    // epilogue
    float inv = 1.0f / l;
    unsigned short* orow = o + (size_t)(tokb + wq0 + c) * DMODEL + h * HDIM + g * 4;
    #pragma unroll
    for (int dt = 0; dt < 8; ++dt) {
        ushort4 ov;
        ov.x = f2bf(oacc[dt][0] * inv);
        ov.y = f2bf(oacc[dt][1] * inv);
        ov.z = f2bf(oacc[dt][2] * inv);
        ov.w = f2bf(oacc[dt][3] * inv);
        *(ushort4*)(orow + dt * 16) = ov;
    }
}

// ---------------------------------------------------------------------------
// Launch
// ---------------------------------------------------------------------------
extern "C" void kernel_launch(void* const* d_in, const int* in_sizes, int n_in,
                              void* d_out, int out_size, void* d_ws, size_t ws_size,
                              hipStream_t stream)
{
    const int*   tokens       = (const int*)  d_in[0];
    const float* tok_emb      = (const float*)d_in[1];
    const float* pos_emb      = (const float*)d_in[2];
    const float* attn_norm_w  = (const float*)d_in[3];
    const float* Wq           = (const float*)d_in[4];
    const float* Wk           = (const float*)d_in[5];
    const float* Wv           = (const float*)d_in[6];
    const float* Wo           = (const float*)d_in[7];
    const float* mlp_norm_w   = (const float*)d_in[8];
    const float* W1           = (const float*)d_in[9];
    const float* W2           = (const float*)d_in[10];
    const float* final_norm_w = (const float*)d_in[11];
    float* out = (float*)d_out;

    // ---- workspace layout ----
    char* wp = (char*)d_ws;
    size_t off = 0;
    auto alloc = [&](size_t bytes) -> void* {
        void* p = wp + off;
        off += (bytes + 255) & ~(size_t)255;
        return p;
    };
    float* x            = (float*)alloc((size_t)NTOK * DMODEL * 4);
    unsigned short* nbf    = (unsigned short*)alloc((size_t)NTOK * DMODEL * 2);
    unsigned short* qkbf   = (unsigned short*)alloc((size_t)NTOK * QKLD * 2);
    unsigned short* vtb    = (unsigned short*)alloc((size_t)DMODEL * NTOK * 2);
    unsigned short* attnbf = (unsigned short*)alloc((size_t)NTOK * DMODEL * 2);
    unsigned short* hbf    = (unsigned short*)alloc((size_t)NTOK * FFDIM * 2);
    unsigned short* temb   = (unsigned short*)alloc((size_t)VPAD * DMODEL * 2);
    unsigned short* Wqk_t  = (unsigned short*)alloc((size_t)NLAYER * QKLD * DMODEL * 2);
    unsigned short* Wv_t   = (unsigned short*)alloc((size_t)NLAYER * DMODEL * DMODEL * 2);
    unsigned short* Wo_t   = (unsigned short*)alloc((size_t)NLAYER * DMODEL * DMODEL * 2);
    unsigned short* W1_t   = (unsigned short*)alloc((size_t)NLAYER * DMODEL * FFDIM * 2);
    unsigned short* W2_t   = (unsigned short*)alloc((size_t)NLAYER * FFDIM * DMODEL * 2);
    if (off > ws_size) return;

    // ---- weight prep ----
    {
        dim3 bb(32, 8), g(HDIM / 32, DMODEL / 32, NLAYER * NHEAD);
        transpose_qkv_kernel<<<g, bb, 0, stream>>>(Wq, Wqk_t, 0);
        transpose_qkv_kernel<<<g, bb, 0, stream>>>(Wk, Wqk_t, DMODEL);
        transpose_cast_kernel<<<g, bb, 0, stream>>>(Wv, Wv_t, DMODEL, HDIM);
    }
    {
        dim3 bb(32, 8), g(DMODEL / 32, DMODEL / 32, NLAYER);
        transpose_cast_kernel<<<g, bb, 0, stream>>>(Wo, Wo_t, DMODEL, DMODEL);
    }
    {
        dim3 bb(32, 8), g(FFDIM / 32, DMODEL / 32, NLAYER);
        transpose_cast_kernel<<<g, bb, 0, stream>>>(W1, W1_t, DMODEL, FFDIM);
    }
    {
        dim3 bb(32, 8), g(DMODEL / 32, FFDIM / 32, NLAYER);
        transpose_cast_kernel<<<g, bb, 0, stream>>>(W2, W2_t, FFDIM, DMODEL);
    }
    {
        long n_src = (long)VOCAB * DMODEL, n_tot = (long)VPAD * DMODEL;
        cast_pad_kernel<<<(unsigned)(n_tot / 8 / 256), 256, 0, stream>>>(
            tok_emb, temb, n_src, n_tot);
    }

    // ---- embed ----
    embed_kernel<<<(NTOK * DMODEL) / 256, 256, 0, stream>>>(tokens, tok_emb, pos_emb, x);

    const size_t LW   = (size_t)DMODEL * DMODEL;
    const size_t LWQK = (size_t)QKLD * DMODEL;
    const size_t LWF  = (size_t)DMODEL * FFDIM;

    for (int l = 0; l < NLAYER; l++) {
        rmsnorm_bf_kernel<<<NTOK, 256, 0, stream>>>(x, attn_norm_w + (size_t)l * DMODEL, nbf);
        // q|k combined: [NTOK][2048]
        mm_kernel<false, false, true, 0><<<16 * 16, 256, 0, stream>>>(
            nbf, Wqk_t + l * LWQK, qkbf, NTOK, QKLD, DMODEL, 16);
        // Vt[hd][token] = Wv_t . n^T (swapped-role GEMM)
        mm_kernel<false, false, true, 0><<<8 * 16, 256, 0, stream>>>(
            Wv_t + l * LW, nbf, vtb, DMODEL, NTOK, DMODEL, 8);
        flash_attn_kernel<<<dim3(SEQ / 64, NHEAD, BATCH), 256, 0, stream>>>(
            qkbf, qkbf + DMODEL, vtb, attnbf);
        mm_kernel<true, false, false, 0><<<16 * 8, 256, 0, stream>>>(
            attnbf, Wo_t + l * LW, x, NTOK, DMODEL, DMODEL, 16);
        rmsnorm_bf_kernel<<<NTOK, 256, 0, stream>>>(x, mlp_norm_w + (size_t)l * DMODEL, nbf);
        mm_kernel<false, true, true, 0><<<16 * 32, 256, 0, stream>>>(
            nbf, W1_t + l * LWF, hbf, NTOK, FFDIM, DMODEL, 16);
        mm_kernel<true, false, false, 0><<<16 * 8, 256, 0, stream>>>(
            hbf, W2_t + l * LWF, x, NTOK, DMODEL, FFDIM, 16);
    }

    rmsnorm_bf_kernel<<<NTOK, 256, 0, stream>>>(x, final_norm_w, nbf);
    // lm-head: 16 rows x 393 cols = 6288 blocks, col-major + XCD swizzle
    mm_kernel<false, false, false, 1><<<16 * 393, 256, 0, stream>>>(
        nbf, temb, out, NTOK, VOCAB, DMODEL, 16);
}

// Round 7
// 2366.105 us; speedup vs baseline: 5.3042x; 1.0394x over previous
//
#include <hip/hip_runtime.h>
#include <hip/hip_bf16.h>
#include <cstddef>
#include <cstdint>

// Model dims (fixed by the reference)
#define VOCAB 50257
#define VPAD  50432              // 197 * 256 (lm-head B rows padded for 256-tile)
#define DMODEL 1024
#define NHEAD 8
#define NLAYER 6
#define SEQ 1024
#define BATCH 2
#define HDIM 128
#define FFDIM 4096
#define NTOK (SEQ * BATCH)       // 2048 tokens
#define QKLD 2048                // q/k combined row stride
#define EPSV 1e-5f

// Token layout is BATCH-MAJOR throughout: token' = b*SEQ + s.

typedef __attribute__((ext_vector_type(8))) short short8;
typedef __attribute__((ext_vector_type(4))) float f32x4;

__device__ __forceinline__ unsigned short f2bf(float f) {
    union { float f; unsigned u; } v; v.f = f;
    unsigned r = v.u + 0x7FFF + ((v.u >> 16) & 1);   // round-to-nearest-even
    return (unsigned short)(r >> 16);
}

// ---------------------------------------------------------------------------
// Embedding (batch-major)
// ---------------------------------------------------------------------------
__global__ __launch_bounds__(256) void embed_kernel(
    const int* __restrict__ tokens, const float* __restrict__ tok_emb,
    const float* __restrict__ pos_emb, float* __restrict__ x)
{
    int idx = blockIdx.x * 256 + threadIdx.x;
    int t = idx >> 10;                    // b*SEQ + s
    int d = idx & (DMODEL - 1);
    int b = t >> 10, s = t & (SEQ - 1);
    int tok = tokens[s * BATCH + b];
    x[idx] = tok_emb[(size_t)tok * DMODEL + d] + pos_emb[(size_t)s * DMODEL + d];
}

// ---------------------------------------------------------------------------
// RMSNorm f32 -> bf16
// ---------------------------------------------------------------------------
__global__ __launch_bounds__(256) void rmsnorm_bf_kernel(
    const float* __restrict__ x, const float* __restrict__ w,
    unsigned short* __restrict__ o)
{
    int t = blockIdx.x;
    int tid = threadIdx.x;
    const float4 xv = ((const float4*)(x + (size_t)t * DMODEL))[tid];
    float ss = xv.x * xv.x + xv.y * xv.y + xv.z * xv.z + xv.w * xv.w;
    __shared__ float red[256];
    red[tid] = ss;
    __syncthreads();
    for (int off = 128; off > 0; off >>= 1) {
        if (tid < off) red[tid] += red[tid + off];
        __syncthreads();
    }
    float inv = rsqrtf(red[0] * (1.0f / DMODEL) + EPSV);
    const float4 wv = ((const float4*)w)[tid];
    ushort4 ov;
    ov.x = f2bf(wv.x * xv.x * inv);
    ov.y = f2bf(wv.y * xv.y * inv);
    ov.z = f2bf(wv.z * xv.z * inv);
    ov.w = f2bf(wv.w * xv.w * inv);
    ((ushort4*)(o + (size_t)t * DMODEL))[tid] = ov;
}

// ---------------------------------------------------------------------------
// Batched transpose + cast: in [z][R][C] f32 -> out [z][C][R] bf16
// ---------------------------------------------------------------------------
__global__ __launch_bounds__(256) void transpose_cast_kernel(
    const float* __restrict__ in, unsigned short* __restrict__ out, int R, int C)
{
    __shared__ float tile[32][33];
    const size_t bo = (size_t)blockIdx.z * R * C;
    const float* src = in + bo;
    unsigned short* dst = out + bo;
    int c0 = blockIdx.x * 32, r0 = blockIdx.y * 32;
    int tx = threadIdx.x, ty = threadIdx.y;
    #pragma unroll
    for (int i = 0; i < 32; i += 8)
        tile[ty + i][tx] = src[(size_t)(r0 + ty + i) * C + c0 + tx];
    __syncthreads();
    #pragma unroll
    for (int i = 0; i < 32; i += 8)
        dst[(size_t)(c0 + ty + i) * R + r0 + tx] = f2bf(tile[tx][ty + i]);
}

// ---------------------------------------------------------------------------
// Q/K weight transpose into combined Wqk_t [l][2048][1024] at row offset.
// ---------------------------------------------------------------------------
__global__ __launch_bounds__(256) void transpose_qkv_kernel(
    const float* __restrict__ in, unsigned short* __restrict__ out, int row_off)
{
    __shared__ float tile[32][33];
    int z = blockIdx.z;
    int l = z >> 3, h = z & 7;
    const float* src = in + (size_t)z * DMODEL * HDIM;
    unsigned short* dst = out + (size_t)l * QKLD * DMODEL
                              + (size_t)(row_off + h * HDIM) * DMODEL;
    int c0 = blockIdx.x * 32, r0 = blockIdx.y * 32;
    int tx = threadIdx.x, ty = threadIdx.y;
    #pragma unroll
    for (int i = 0; i < 32; i += 8)
        tile[ty + i][tx] = src[(size_t)(r0 + ty + i) * HDIM + c0 + tx];
    __syncthreads();
    #pragma unroll
    for (int i = 0; i < 32; i += 8)
        dst[(size_t)(c0 + ty + i) * DMODEL + r0 + tx] = f2bf(tile[tx][ty + i]);
}

// ---------------------------------------------------------------------------
// f32 -> bf16 flat cast with zero padding
// ---------------------------------------------------------------------------
__global__ __launch_bounds__(256) void cast_pad_kernel(
    const float* __restrict__ in, unsigned short* __restrict__ out,
    long n_src, long n_tot)
{
    long i = ((long)blockIdx.x * 256 + threadIdx.x) * 8;
    if (i >= n_tot) return;
    short8 o8;
    if (i < n_src) {
        const float4* p = (const float4*)(in + i);
        float4 a = p[0], b = p[1];
        o8[0] = (short)f2bf(a.x); o8[1] = (short)f2bf(a.y);
        o8[2] = (short)f2bf(a.z); o8[3] = (short)f2bf(a.w);
        o8[4] = (short)f2bf(b.x); o8[5] = (short)f2bf(b.y);
        o8[6] = (short)f2bf(b.z); o8[7] = (short)f2bf(b.w);
    } else {
        o8 = (short8)0;
    }
    *(short8*)(out + i) = o8;
}

// ---------------------------------------------------------------------------
// m97-style bf16 MFMA GEMM, 128x128 tile (small-grid GEMMs).
// ---------------------------------------------------------------------------
template<bool ACC, bool SILU, bool BF16OUT, int RM>
__global__ __launch_bounds__(256) void mm_kernel(
    const unsigned short* __restrict__ A, const unsigned short* __restrict__ Bt,
    void* __restrict__ Cv, int M, int N, int K, int rows)
{
    int nwg = gridDim.x;
    int flat = blockIdx.x;
    int q8 = nwg >> 3, r8 = nwg & 7;
    int xcd = flat & 7, lid = flat >> 3;
    int wg = (r8 == 0) ? (xcd * q8 + lid)
           : ((xcd < r8 ? xcd * (q8 + 1) : r8 * (q8 + 1) + (xcd - r8) * q8) + lid);
    const int row0 = (wg % rows) * 128;
    const int col0 = (wg / rows) * 128;

    __shared__ unsigned short lds[8192];
    const int tid  = threadIdx.x;
    const int lane = tid & 63;
    const int wave = tid >> 6;
    const int wm = wave >> 1, wn = wave & 1;

    f32x4 acc[4][4] = {};

    const int off_base = wave * 4096 + lane * 16;
    const int kfr = (lane >> 4) * 8;
    const int l15 = lane & 15;

    for (int k0 = 0; k0 < K; k0 += 32) {
        #pragma unroll
        for (int c = 0; c < 4; ++c) {
            int off  = off_base + c * 1024;
            int row  = (off & 8191) >> 6;
            int koff = (off >> 1) & 31;
            const unsigned short* src = (off < 8192)
                ? A  + (size_t)(row0 + row) * K + k0 + koff
                : Bt + (size_t)(col0 + row) * K + k0 + koff;
            unsigned short* dst = lds + ((wave * 4096 + c * 1024) >> 1);
            __builtin_amdgcn_global_load_lds(
                (const __attribute__((address_space(1))) void*)src,
                (__attribute__((address_space(3))) void*)dst, 16, 0, 0);
        }
        __syncthreads();

        short8 af[4], bfr[4];
        #pragma unroll
        for (int i = 0; i < 4; ++i)
            af[i] = *(const short8*)&lds[(wm * 64 + i * 16 + l15) * 32 + kfr];
        #pragma unroll
        for (int j = 0; j < 4; ++j)
            bfr[j] = *(const short8*)&lds[4096 + (wn * 64 + j * 16 + l15) * 32 + kfr];
        #pragma unroll
        for (int i = 0; i < 4; ++i)
            #pragma unroll
            for (int j = 0; j < 4; ++j)
                acc[i][j] = __builtin_amdgcn_mfma_f32_16x16x32_bf16(
                    af[i], bfr[j], acc[i][j], 0, 0, 0);
        __syncthreads();
    }

    float* Cf = (float*)Cv;
    unsigned short* Cb = (unsigned short*)Cv;
    const int crow  = row0 + wm * 64 + ((lane >> 4) << 2);
    const int ccol0 = col0 + wn * 64 + l15;
    #pragma unroll
    for (int i = 0; i < 4; ++i) {
        #pragma unroll
        for (int j = 0; j < 4; ++j) {
            int gcol = ccol0 + j * 16;
            if (gcol < N) {
                #pragma unroll
                for (int r = 0; r < 4; ++r) {
                    int grow = crow + i * 16 + r;
                    int orow = RM ? (((grow & (SEQ - 1)) << 1) | (grow >> 10)) : grow;
                    float v = acc[i][j][r];
                    if (SILU) v = v / (1.0f + __expf(-v));
                    size_t ci = (size_t)orow * N + gcol;
                    if (BF16OUT)      Cb[ci] = f2bf(v);
                    else if (ACC)     Cf[ci] += v;
                    else              Cf[ci] = v;
                }
            }
        }
    }
}

// ---------------------------------------------------------------------------
// 256x256-tile bf16 MFMA GEMM, 8 waves (512 thr), BK=32, 4-deep LDS ring
// (4 x 32KB = 128KB), counted vmcnt (never 0 in-loop), raw s_barrier,
// XOR-swizzled LDS (slot ^= (row>>1)&3 on 16B slots; pre-swizzled global
// source + swizzled ds_read — rule #21 both-sides), setprio around MFMA.
// C[M][N] = A[M][K] * Bt[N][K]^T.  M%256==0, K%32==0, K>=96; Bt rows padded
// to 256 multiple. rows = M/256; grid = rows * ceil(N/256) (col-major + XCD).
// ---------------------------------------------------------------------------
template<bool SILU, bool BF16OUT, int RM>
__global__ __launch_bounds__(512, 1) void mm256_kernel(
    const unsigned short* __restrict__ A, const unsigned short* __restrict__ Bt,
    void* __restrict__ Cv, int M, int N, int K, int rows)
{
    int nwg = gridDim.x;
    int flat = blockIdx.x;
    int q8 = nwg >> 3, r8 = nwg & 7;
    int xcd = flat & 7, lid = flat >> 3;
    int wg = (r8 == 0) ? (xcd * q8 + lid)
           : ((xcd < r8 ? xcd * (q8 + 1) : r8 * (q8 + 1) + (xcd - r8) * q8) + lid);
    const int row0 = (wg % rows) * 256;
    const int col0 = (wg / rows) * 256;

    __shared__ __align__(16) char lds[131072];   // 4 bufs x (A 16KB + B 16KB)
    const int tid  = threadIdx.x;
    const int lane = tid & 63;
    const int wave = tid >> 6;
    const int wm = wave >> 2;          // 0..1 -> 128-row half
    const int wn = wave & 3;           // 0..3 -> 64-col slice
    const int g  = lane >> 4;          // 0..3
    const int c  = lane & 15;

    f32x4 acc[8][4] = {};

    // stage one K-tile (32KB) into buffer buf: 4 global_load_lds per thread.
    auto STAGE = [&](int buf, int tile) {
        const int k0 = tile * 32;
        char* base = lds + buf * 32768;
        #pragma unroll
        for (int j = 0; j < 2; ++j) {
            int chunk = j * 512 + tid;             // 1024 chunks of 16B (A)
            int row = chunk >> 2, slot = chunk & 3;
            int sslot = slot ^ ((row >> 1) & 3);   // pre-swizzled source
            __builtin_amdgcn_global_load_lds(
                (const __attribute__((address_space(1))) void*)
                    (A + (size_t)(row0 + row) * K + k0 + sslot * 8),
                (__attribute__((address_space(3))) void*)(base + chunk * 16),
                16, 0, 0);
        }
        #pragma unroll
        for (int j = 0; j < 2; ++j) {
            int chunk = j * 512 + tid;             // 1024 chunks of 16B (B)
            int row = chunk >> 2, slot = chunk & 3;
            int sslot = slot ^ ((row >> 1) & 3);
            __builtin_amdgcn_global_load_lds(
                (const __attribute__((address_space(1))) void*)
                    (Bt + (size_t)(col0 + row) * K + k0 + sslot * 8),
                (__attribute__((address_space(3))) void*)(base + 16384 + chunk * 16),
                16, 0, 0);
        }
    };

    const int NT = K >> 5;
    // prologue: 3 tiles in flight
    STAGE(0, 0); STAGE(1, 1); STAGE(2, 2);
    asm volatile("s_waitcnt vmcnt(8)" ::: "memory");   // tile 0 landed
    __builtin_amdgcn_s_barrier();
    __builtin_amdgcn_sched_barrier(0);

    for (int t = 0; t < NT; ++t) {
        if (t + 3 < NT) STAGE((t + 3) & 3, t + 3);

        char* base = lds + (t & 3) * 32768;
        short8 af[8], bf[4];
        #pragma unroll
        for (int mf = 0; mf < 8; ++mf) {
            int row = wm * 128 + mf * 16 + c;
            af[mf] = *(const short8*)(base + row * 64 + ((g ^ ((row >> 1) & 3)) << 4));
        }
        #pragma unroll
        for (int nf = 0; nf < 4; ++nf) {
            int row = wn * 64 + nf * 16 + c;
            bf[nf] = *(const short8*)(base + 16384 + row * 64 + ((g ^ ((row >> 1) & 3)) << 4));
        }
        __builtin_amdgcn_s_setprio(1);
        #pragma unroll
        for (int mf = 0; mf < 8; ++mf)
            #pragma unroll
            for (int nf = 0; nf < 4; ++nf)
                acc[mf][nf] = __builtin_amdgcn_mfma_f32_16x16x32_bf16(
                    af[mf], bf[nf], acc[mf][nf], 0, 0, 0);
        __builtin_amdgcn_s_setprio(0);
        __builtin_amdgcn_sched_barrier(0);

        if (t + 1 < NT) {
            // ensure tile t+1 landed: allowed in-flight = stages for {t+2,t+3}
            if (t + 3 < NT)      asm volatile("s_waitcnt vmcnt(8)" ::: "memory");
            else if (t + 2 < NT) asm volatile("s_waitcnt vmcnt(4)" ::: "memory");
            else                 asm volatile("s_waitcnt vmcnt(0)" ::: "memory");
            __builtin_amdgcn_s_barrier();
            __builtin_amdgcn_sched_barrier(0);
        }
    }

    float* Cf = (float*)Cv;
    unsigned short* Cb = (unsigned short*)Cv;
    #pragma unroll
    for (int mf = 0; mf < 8; ++mf) {
        #pragma unroll
        for (int nf = 0; nf < 4; ++nf) {
            int gcol = col0 + wn * 64 + nf * 16 + c;
            if (gcol < N) {
                #pragma unroll
                for (int r = 0; r < 4; ++r) {
                    int grow = row0 + wm * 128 + mf * 16 + g * 4 + r;
                    int orow = RM ? (((grow & (SEQ - 1)) << 1) | (grow >> 10)) : grow;
                    float v = acc[mf][nf][r];
                    if (SILU) v = v / (1.0f + __expf(-v));
                    size_t ci = (size_t)orow * N + gcol;
                    if (BF16OUT) Cb[ci] = f2bf(v);
                    else         Cf[ci] = v;
                }
            }
        }
    }
}

// ---------------------------------------------------------------------------
// Flash attention (bf16 MFMA) — unchanged from round 5.
// ---------------------------------------------------------------------------
__global__ __launch_bounds__(256) void flash_attn_kernel(
    const unsigned short* __restrict__ q, const unsigned short* __restrict__ k,
    const unsigned short* __restrict__ vt, unsigned short* __restrict__ o)
{
    const int qt   = blockIdx.x;
    const int h    = blockIdx.y;
    const int b    = blockIdx.z;
    const int tid  = threadIdx.x;
    const int lane = tid & 63;
    const int wave = tid >> 6;
    const int g    = lane >> 4;
    const int c    = lane & 15;

    __shared__ unsigned short k_lds[64 * 128];
    __shared__ unsigned short vt_lds[128 * 64];
    __shared__ unsigned short p_lds[4 * 16 * 64];

    const int q0  = qt * 64;
    const int wq0 = q0 + wave * 16;
    const int tokb = b * SEQ;

    short8 qf[4];
    {
        const unsigned short* qr =
            q + (size_t)(tokb + wq0 + c) * QKLD + h * HDIM + g * 8;
        #pragma unroll
        for (int dblk = 0; dblk < 4; ++dblk)
            qf[dblk] = *(const short8*)(qr + dblk * 32);
    }

    f32x4 oacc[8] = {};
    float m = -1e30f, l = 0.f;
    const float scale = 0.08838834764831845f;
    const int myq = wq0 + c;

    const int nt = qt + 1;
    for (int it = 0; it < nt; ++it) {
        const int kv0 = it * 64;
        short8 kc[4], vc[4];
        #pragma unroll
        for (int i = 0; i < 4; ++i) {
            int chunk = tid + i * 256;
            int key = chunk >> 4, cc = chunk & 15;
            kc[i] = *(const short8*)(
                k + (size_t)(tokb + kv0 + key) * QKLD + h * HDIM + cc * 8);
        }
        #pragma unroll
        for (int i = 0; i < 4; ++i) {
            int chunk = tid + i * 256;
            int d = chunk >> 3, cc = chunk & 7;
            vc[i] = *(const short8*)(
                vt + (size_t)(h * HDIM + d) * NTOK + tokb + kv0 + cc * 8);
        }
        __syncthreads();
        #pragma unroll
        for (int i = 0; i < 4; ++i) {
            int chunk = tid + i * 256;
            int key = chunk >> 4, cc = chunk & 15;
            *(short8*)((char*)k_lds + ((key * 256 + cc * 16) ^ ((key & 7) << 4))) = kc[i];
        }
        #pragma unroll
        for (int i = 0; i < 4; ++i) {
            int chunk = tid + i * 256;
            int d = chunk >> 3, cc = chunk & 7;
            *(short8*)((char*)vt_lds + ((d * 128 + cc * 16) ^ ((d & 7) << 4))) = vc[i];
        }
        __syncthreads();

        f32x4 st[4];
        #pragma unroll
        for (int sub = 0; sub < 4; ++sub) {
            f32x4 acc = {};
            int key = sub * 16 + c;
            #pragma unroll
            for (int dblk = 0; dblk < 4; ++dblk) {
                short8 kf = *(const short8*)((char*)k_lds +
                    ((key * 256 + dblk * 64 + g * 16) ^ ((key & 7) << 4)));
                acc = __builtin_amdgcn_mfma_f32_16x16x32_bf16(kf, qf[dblk], acc, 0, 0, 0);
            }
            st[sub] = acc;
        }

        #pragma unroll
        for (int sub = 0; sub < 4; ++sub)
            #pragma unroll
            for (int r = 0; r < 4; ++r) {
                int key = kv0 + sub * 16 + g * 4 + r;
                float s = st[sub][r] * scale;
                st[sub][r] = (key <= myq) ? s : -1e30f;
            }

        float tm = -1e30f;
        #pragma unroll
        for (int sub = 0; sub < 4; ++sub)
            #pragma unroll
            for (int r = 0; r < 4; ++r) tm = fmaxf(tm, st[sub][r]);
        tm = fmaxf(tm, __shfl_xor(tm, 16));
        tm = fmaxf(tm, __shfl_xor(tm, 32));
        float mnew = fmaxf(m, tm);
        float sc_f = __expf(m - mnew);
        m = mnew;

        float ps = 0.f;
        #pragma unroll
        for (int sub = 0; sub < 4; ++sub) {
            float p0 = __expf(st[sub][0] - m);
            float p1 = __expf(st[sub][1] - m);
            float p2 = __expf(st[sub][2] - m);
            float p3 = __expf(st[sub][3] - m);
            ps += (p0 + p1) + (p2 + p3);
            ushort4 pk;
            pk.x = f2bf(p0); pk.y = f2bf(p1); pk.z = f2bf(p2); pk.w = f2bf(p3);
            *(ushort4*)((char*)p_lds + wave * 2048 +
                ((c * 128 + sub * 32 + g * 8) ^ ((c & 7) << 4))) = pk;
        }
        ps += __shfl_xor(ps, 16);
        ps += __shfl_xor(ps, 32);
        l = l * sc_f + ps;
        #pragma unroll
        for (int dt = 0; dt < 8; ++dt)
            #pragma unroll
            for (int r = 0; r < 4; ++r) oacc[dt][r] *= sc_f;

        #pragma unroll
        for (int kb = 0; kb < 2; ++kb) {
            short8 pf = *(const short8*)((char*)p_lds + wave * 2048 +
                ((c * 128 + kb * 64 + g * 16) ^ ((c & 7) << 4)));
            #pragma unroll
            for (int dt = 0; dt < 8; ++dt) {
                int d = dt * 16 + c;
                short8 vf = *(const short8*)((char*)vt_lds +
                    ((d * 128 + kb * 64 + g * 16) ^ ((d & 7) << 4)));
                oacc[dt] = __builtin_amdgcn_mfma_f32_16x16x32_bf16(vf, pf, oacc[dt], 0, 0, 0);
            }
        }
    }

    float inv = 1.0f / l;
    unsigned short* orow = o + (size_t)(tokb + wq0 + c) * DMODEL + h * HDIM + g * 4;
    #pragma unroll
    for (int dt = 0; dt < 8; ++dt) {
        ushort4 ov;
        ov.x = f2bf(oacc[dt][0] * inv);
        ov.y = f2bf(oacc[dt][1] * inv);
        ov.z = f2bf(oacc[dt][2] * inv);
        ov.w = f2bf(oacc[dt][3] * inv);
        *(ushort4*)(orow + dt * 16) = ov;
    }
}

// ---------------------------------------------------------------------------
// Launch
// ---------------------------------------------------------------------------
extern "C" void kernel_launch(void* const* d_in, const int* in_sizes, int n_in,
                              void* d_out, int out_size, void* d_ws, size_t ws_size,
                              hipStream_t stream)
{
    const int*   tokens       = (const int*)  d_in[0];
    const float* tok_emb      = (const float*)d_in[1];
    const float* pos_emb      = (const float*)d_in[2];
    const float* attn_norm_w  = (const float*)d_in[3];
    const float* Wq           = (const float*)d_in[4];
    const float* Wk           = (const float*)d_in[5];
    const float* Wv           = (const float*)d_in[6];
    const float* Wo           = (const float*)d_in[7];
    const float* mlp_norm_w   = (const float*)d_in[8];
    const float* W1           = (const float*)d_in[9];
    const float* W2           = (const float*)d_in[10];
    const float* final_norm_w = (const float*)d_in[11];
    float* out = (float*)d_out;

    // ---- workspace layout ----
    char* wp = (char*)d_ws;
    size_t off = 0;
    auto alloc = [&](size_t bytes) -> void* {
        void* p = wp + off;
        off += (bytes + 255) & ~(size_t)255;
        return p;
    };
    float* x            = (float*)alloc((size_t)NTOK * DMODEL * 4);
    unsigned short* nbf    = (unsigned short*)alloc((size_t)NTOK * DMODEL * 2);
    unsigned short* qkbf   = (unsigned short*)alloc((size_t)NTOK * QKLD * 2);
    unsigned short* vtb    = (unsigned short*)alloc((size_t)DMODEL * NTOK * 2);
    unsigned short* attnbf = (unsigned short*)alloc((size_t)NTOK * DMODEL * 2);
    unsigned short* hbf    = (unsigned short*)alloc((size_t)NTOK * FFDIM * 2);
    unsigned short* temb   = (unsigned short*)alloc((size_t)VPAD * DMODEL * 2);
    unsigned short* Wqk_t  = (unsigned short*)alloc((size_t)NLAYER * QKLD * DMODEL * 2);
    unsigned short* Wv_t   = (unsigned short*)alloc((size_t)NLAYER * DMODEL * DMODEL * 2);
    unsigned short* Wo_t   = (unsigned short*)alloc((size_t)NLAYER * DMODEL * DMODEL * 2);
    unsigned short* W1_t   = (unsigned short*)alloc((size_t)NLAYER * DMODEL * FFDIM * 2);
    unsigned short* W2_t   = (unsigned short*)alloc((size_t)NLAYER * FFDIM * DMODEL * 2);
    if (off > ws_size) return;

    // ---- weight prep ----
    {
        dim3 bb(32, 8), g(HDIM / 32, DMODEL / 32, NLAYER * NHEAD);
        transpose_qkv_kernel<<<g, bb, 0, stream>>>(Wq, Wqk_t, 0);
        transpose_qkv_kernel<<<g, bb, 0, stream>>>(Wk, Wqk_t, DMODEL);
        transpose_cast_kernel<<<g, bb, 0, stream>>>(Wv, Wv_t, DMODEL, HDIM);
    }
    {
        dim3 bb(32, 8), g(DMODEL / 32, DMODEL / 32, NLAYER);
        transpose_cast_kernel<<<g, bb, 0, stream>>>(Wo, Wo_t, DMODEL, DMODEL);
    }
    {
        dim3 bb(32, 8), g(FFDIM / 32, DMODEL / 32, NLAYER);
        transpose_cast_kernel<<<g, bb, 0, stream>>>(W1, W1_t, DMODEL, FFDIM);
    }
    {
        dim3 bb(32, 8), g(DMODEL / 32, FFDIM / 32, NLAYER);
        transpose_cast_kernel<<<g, bb, 0, stream>>>(W2, W2_t, FFDIM, DMODEL);
    }
    {
        long n_src = (long)VOCAB * DMODEL, n_tot = (long)VPAD * DMODEL;
        cast_pad_kernel<<<(unsigned)(n_tot / 8 / 256), 256, 0, stream>>>(
            tok_emb, temb, n_src, n_tot);
    }

    // ---- embed ----
    embed_kernel<<<(NTOK * DMODEL) / 256, 256, 0, stream>>>(tokens, tok_emb, pos_emb, x);

    const size_t LW   = (size_t)DMODEL * DMODEL;
    const size_t LWQK = (size_t)QKLD * DMODEL;
    const size_t LWF  = (size_t)DMODEL * FFDIM;

    for (int l = 0; l < NLAYER; l++) {
        rmsnorm_bf_kernel<<<NTOK, 256, 0, stream>>>(x, attn_norm_w + (size_t)l * DMODEL, nbf);
        // q|k combined: [NTOK][2048]
        mm_kernel<false, false, true, 0><<<16 * 16, 256, 0, stream>>>(
            nbf, Wqk_t + l * LWQK, qkbf, NTOK, QKLD, DMODEL, 16);
        // Vt[hd][token] = Wv_t . n^T (swapped-role GEMM)
        mm_kernel<false, false, true, 0><<<8 * 16, 256, 0, stream>>>(
            Wv_t + l * LW, nbf, vtb, DMODEL, NTOK, DMODEL, 8);
        flash_attn_kernel<<<dim3(SEQ / 64, NHEAD, BATCH), 256, 0, stream>>>(
            qkbf, qkbf + DMODEL, vtb, attnbf);
        mm_kernel<true, false, false, 0><<<16 * 8, 256, 0, stream>>>(
            attnbf, Wo_t + l * LW, x, NTOK, DMODEL, DMODEL, 16);
        rmsnorm_bf_kernel<<<NTOK, 256, 0, stream>>>(x, mlp_norm_w + (size_t)l * DMODEL, nbf);
        // h = silu(n @ W1): 256-tile kernel, 8 rows x 16 cols = 128 blocks
        mm256_kernel<true, true, 0><<<8 * 16, 512, 0, stream>>>(
            nbf, W1_t + l * LWF, hbf, NTOK, FFDIM, DMODEL, 8);
        mm_kernel<true, false, false, 0><<<16 * 8, 256, 0, stream>>>(
            hbf, W2_t + l * LWF, x, NTOK, DMODEL, FFDIM, 16);
    }

    rmsnorm_bf_kernel<<<NTOK, 256, 0, stream>>>(x, final_norm_w, nbf);
    // lm-head: 256-tile kernel, 8 rows x 197 cols = 1576 blocks
    mm256_kernel<false, false, 1><<<8 * 197, 512, 0, stream>>>(
        nbf, temb, out, NTOK, VOCAB, DMODEL, 8);
}

// Round 8
// 1414.876 us; speedup vs baseline: 8.8702x; 1.6723x over previous
//
#include <hip/hip_runtime.h>
#include <hip/hip_bf16.h>
#include <cstddef>
#include <cstdint>

// Model dims (fixed by the reference)
#define VOCAB 50257
#define VPAD  50432              // 197 * 256 (lm-head B rows padded for 256-tile)
#define DMODEL 1024
#define NHEAD 8
#define NLAYER 6
#define SEQ 1024
#define BATCH 2
#define HDIM 128
#define FFDIM 4096
#define NTOK (SEQ * BATCH)       // 2048 tokens
#define QKVLD 3072               // fused q|k|v row stride
#define EPSV 1e-5f

// Token layout is BATCH-MAJOR throughout: token' = b*SEQ + s.

typedef __attribute__((ext_vector_type(8))) short short8;
typedef __attribute__((ext_vector_type(4))) float f32x4;

__device__ __forceinline__ unsigned short f2bf(float f) {
    union { float f; unsigned u; } v; v.f = f;
    unsigned r = v.u + 0x7FFF + ((v.u >> 16) & 1);   // round-to-nearest-even
    return (unsigned short)(r >> 16);
}

// ---------------------------------------------------------------------------
// Embedding (batch-major)
// ---------------------------------------------------------------------------
__global__ __launch_bounds__(256) void embed_kernel(
    const int* __restrict__ tokens, const float* __restrict__ tok_emb,
    const float* __restrict__ pos_emb, float* __restrict__ x)
{
    int idx = blockIdx.x * 256 + threadIdx.x;
    int t = idx >> 10;                    // b*SEQ + s
    int d = idx & (DMODEL - 1);
    int b = t >> 10, s = t & (SEQ - 1);
    int tok = tokens[s * BATCH + b];
    x[idx] = tok_emb[(size_t)tok * DMODEL + d] + pos_emb[(size_t)s * DMODEL + d];
}

// ---------------------------------------------------------------------------
// RMSNorm f32 -> bf16
// ---------------------------------------------------------------------------
__global__ __launch_bounds__(256) void rmsnorm_bf_kernel(
    const float* __restrict__ x, const float* __restrict__ w,
    unsigned short* __restrict__ o)
{
    int t = blockIdx.x;
    int tid = threadIdx.x;
    const float4 xv = ((const float4*)(x + (size_t)t * DMODEL))[tid];
    float ss = xv.x * xv.x + xv.y * xv.y + xv.z * xv.z + xv.w * xv.w;
    __shared__ float red[256];
    red[tid] = ss;
    __syncthreads();
    for (int off = 128; off > 0; off >>= 1) {
        if (tid < off) red[tid] += red[tid + off];
        __syncthreads();
    }
    float inv = rsqrtf(red[0] * (1.0f / DMODEL) + EPSV);
    const float4 wv = ((const float4*)w)[tid];
    ushort4 ov;
    ov.x = f2bf(wv.x * xv.x * inv);
    ov.y = f2bf(wv.y * xv.y * inv);
    ov.z = f2bf(wv.z * xv.z * inv);
    ov.w = f2bf(wv.w * xv.w * inv);
    ((ushort4*)(o + (size_t)t * DMODEL))[tid] = ov;
}

// ---------------------------------------------------------------------------
// Batched transpose + cast: in [z][R][C] f32 -> out [z][C][R] bf16
// ---------------------------------------------------------------------------
__global__ __launch_bounds__(256) void transpose_cast_kernel(
    const float* __restrict__ in, unsigned short* __restrict__ out, int R, int C)
{
    __shared__ float tile[32][33];
    const size_t bo = (size_t)blockIdx.z * R * C;
    const float* src = in + bo;
    unsigned short* dst = out + bo;
    int c0 = blockIdx.x * 32, r0 = blockIdx.y * 32;
    int tx = threadIdx.x, ty = threadIdx.y;
    #pragma unroll
    for (int i = 0; i < 32; i += 8)
        tile[ty + i][tx] = src[(size_t)(r0 + ty + i) * C + c0 + tx];
    __syncthreads();
    #pragma unroll
    for (int i = 0; i < 32; i += 8)
        dst[(size_t)(c0 + ty + i) * R + r0 + tx] = f2bf(tile[tx][ty + i]);
}

// ---------------------------------------------------------------------------
// Q/K/V weight transpose into combined Wqkv_t [l][3072][1024] at row offset.
// in: [l*H][1024][128] f32. grid (4, 32, L*H), block (32,8).
// ---------------------------------------------------------------------------
__global__ __launch_bounds__(256) void transpose_qkv_kernel(
    const float* __restrict__ in, unsigned short* __restrict__ out, int row_off)
{
    __shared__ float tile[32][33];
    int z = blockIdx.z;
    int l = z >> 3, h = z & 7;
    const float* src = in + (size_t)z * DMODEL * HDIM;
    unsigned short* dst = out + (size_t)l * QKVLD * DMODEL
                              + (size_t)(row_off + h * HDIM) * DMODEL;
    int c0 = blockIdx.x * 32, r0 = blockIdx.y * 32;
    int tx = threadIdx.x, ty = threadIdx.y;
    #pragma unroll
    for (int i = 0; i < 32; i += 8)
        tile[ty + i][tx] = src[(size_t)(r0 + ty + i) * HDIM + c0 + tx];
    __syncthreads();
    #pragma unroll
    for (int i = 0; i < 32; i += 8)
        dst[(size_t)(c0 + ty + i) * DMODEL + r0 + tx] = f2bf(tile[tx][ty + i]);
}

// ---------------------------------------------------------------------------
// Vt transpose: qkv [token][3072] (cols 2048..3071) -> vt [hd][token] bf16
// grid (1024/32, NTOK/32), block (32,8)
// ---------------------------------------------------------------------------
__global__ __launch_bounds__(256) void vt_transpose_kernel(
    const unsigned short* __restrict__ qkv, unsigned short* __restrict__ vt)
{
    __shared__ unsigned short tile[32][33];
    int c0 = blockIdx.x * 32;   // hd
    int r0 = blockIdx.y * 32;   // token
    int tx = threadIdx.x, ty = threadIdx.y;
    #pragma unroll
    for (int i = 0; i < 32; i += 8)
        tile[ty + i][tx] = qkv[(size_t)(r0 + ty + i) * QKVLD + 2048 + c0 + tx];
    __syncthreads();
    #pragma unroll
    for (int i = 0; i < 32; i += 8)
        vt[(size_t)(c0 + ty + i) * NTOK + r0 + tx] = tile[tx][ty + i];
}

// ---------------------------------------------------------------------------
// f32 -> bf16 flat cast with zero padding
// ---------------------------------------------------------------------------
__global__ __launch_bounds__(256) void cast_pad_kernel(
    const float* __restrict__ in, unsigned short* __restrict__ out,
    long n_src, long n_tot)
{
    long i = ((long)blockIdx.x * 256 + threadIdx.x) * 8;
    if (i >= n_tot) return;
    short8 o8;
    if (i < n_src) {
        const float4* p = (const float4*)(in + i);
        float4 a = p[0], b = p[1];
        o8[0] = (short)f2bf(a.x); o8[1] = (short)f2bf(a.y);
        o8[2] = (short)f2bf(a.z); o8[3] = (short)f2bf(a.w);
        o8[4] = (short)f2bf(b.x); o8[5] = (short)f2bf(b.y);
        o8[6] = (short)f2bf(b.z); o8[7] = (short)f2bf(b.w);
    } else {
        o8 = (short8)0;
    }
    *(short8*)(out + i) = o8;
}

// ---------------------------------------------------------------------------
// mm128: 128x128-tile bf16 MFMA GEMM, BK=64, 2-deep LDS double buffer
// (2 x 32KB = 64KB -> 2 blocks/CU), issue-early STAGE + late vmcnt(0),
// raw s_barrier, T2 XOR swizzle slot^=(row&7) (pre-swizzled source + swizzled
// ds_read), setprio around MFMA. Optional split-K with f32 atomicAdd epilogue.
// C[M][N] = A[M][K]*Bt[N][K]^T. M%128==0, N%128==0, K%(64*ksplit)==0.
// grid = cols * rows * ksplit (col-major, sk innermost).
// ---------------------------------------------------------------------------
template<bool ATOMIC, bool SILU, bool BF16OUT>
__global__ __launch_bounds__(256, 2) void mm128_kernel(
    const unsigned short* __restrict__ A, const unsigned short* __restrict__ Bt,
    void* __restrict__ Cv, int M, int N, int K, int rows, int ksplit)
{
    int nwg = gridDim.x;
    int flat = blockIdx.x;
    int q8 = nwg >> 3, r8 = nwg & 7;
    int xcd = flat & 7, lid = flat >> 3;
    int wg = (r8 == 0) ? (xcd * q8 + lid)
           : ((xcd < r8 ? xcd * (q8 + 1) : r8 * (q8 + 1) + (xcd - r8) * q8) + lid);
    int rs = rows * ksplit;
    const int col0 = (wg / rs) * 128;
    int rem = wg % rs;
    const int row0 = (rem / ksplit) * 128;
    const int sk   = rem % ksplit;
    const int Keff = K / ksplit;
    const int kbase = sk * Keff;

    __shared__ __align__(16) char lds[65536];   // 2 bufs x (A 16KB + B 16KB)
    const int tid  = threadIdx.x;
    const int lane = tid & 63;
    const int wave = tid >> 6;
    const int wm = wave >> 1, wn = wave & 1;
    const int g  = lane >> 4;
    const int c  = lane & 15;

    f32x4 acc[4][4] = {};

    auto STAGE = [&](int buf, int t) {
        const int k0 = kbase + t * 64;
        char* base = lds + buf * 32768;
        #pragma unroll
        for (int j = 0; j < 4; ++j) {
            int chunk = j * 256 + tid;            // 1024 chunks of 16B (A)
            int row = chunk >> 3, slot = chunk & 7;
            int ss = slot ^ (row & 7);            // pre-swizzled source
            __builtin_amdgcn_global_load_lds(
                (const __attribute__((address_space(1))) void*)
                    (A + (size_t)(row0 + row) * K + k0 + ss * 8),
                (__attribute__((address_space(3))) void*)(base + chunk * 16), 16, 0, 0);
        }
        #pragma unroll
        for (int j = 0; j < 4; ++j) {
            int chunk = j * 256 + tid;            // 1024 chunks of 16B (B)
            int row = chunk >> 3, slot = chunk & 7;
            int ss = slot ^ (row & 7);
            __builtin_amdgcn_global_load_lds(
                (const __attribute__((address_space(1))) void*)
                    (Bt + (size_t)(col0 + row) * K + k0 + ss * 8),
                (__attribute__((address_space(3))) void*)(base + 16384 + chunk * 16), 16, 0, 0);
        }
    };

    const int NT = Keff >> 6;
    STAGE(0, 0);
    asm volatile("s_waitcnt vmcnt(0)" ::: "memory");
    __builtin_amdgcn_s_barrier();
    __builtin_amdgcn_sched_barrier(0);

    for (int t = 0; t < NT; ++t) {
        if (t + 1 < NT) STAGE((t + 1) & 1, t + 1);   // issue-early (hidden under MFMA)

        char* base = lds + (t & 1) * 32768;
        short8 af[2][4], bf[2][4];
        #pragma unroll
        for (int ks = 0; ks < 2; ++ks) {
            #pragma unroll
            for (int i = 0; i < 4; ++i) {
                int rowa = wm * 64 + i * 16 + c;
                af[ks][i] = *(const short8*)(base + rowa * 128 + (((ks * 4 + g) ^ (rowa & 7)) << 4));
                int rowb = wn * 64 + i * 16 + c;
                bf[ks][i] = *(const short8*)(base + 16384 + rowb * 128 + (((ks * 4 + g) ^ (rowb & 7)) << 4));
            }
        }
        __builtin_amdgcn_s_setprio(1);
        #pragma unroll
        for (int ks = 0; ks < 2; ++ks)
            #pragma unroll
            for (int i = 0; i < 4; ++i)
                #pragma unroll
                for (int j = 0; j < 4; ++j)
                    acc[i][j] = __builtin_amdgcn_mfma_f32_16x16x32_bf16(
                        af[ks][i], bf[ks][j], acc[i][j], 0, 0, 0);
        __builtin_amdgcn_s_setprio(0);

        if (t + 1 < NT) asm volatile("s_waitcnt vmcnt(0)" ::: "memory");
        __builtin_amdgcn_s_barrier();
        __builtin_amdgcn_sched_barrier(0);
    }

    float* Cf = (float*)Cv;
    unsigned short* Cb = (unsigned short*)Cv;
    const int crow  = row0 + wm * 64 + g * 4;
    const int ccol0 = col0 + wn * 64 + c;
    #pragma unroll
    for (int i = 0; i < 4; ++i) {
        #pragma unroll
        for (int j = 0; j < 4; ++j) {
            int gcol = ccol0 + j * 16;
            #pragma unroll
            for (int r = 0; r < 4; ++r) {
                int grow = crow + i * 16 + r;
                float v = acc[i][j][r];
                if (SILU) v = v / (1.0f + __expf(-v));
                size_t ci = (size_t)grow * N + gcol;
                if (ATOMIC)       atomicAdd(&Cf[ci], v);
                else if (BF16OUT) Cb[ci] = f2bf(v);
                else              Cf[ci] = v;
            }
        }
    }
}

// ---------------------------------------------------------------------------
// mm256: 256x256-tile, 8 waves, BK=32, 4-deep ring, counted vmcnt (unchanged
// from round 6 — used for W1-sized? no: lm-head only now).
// ---------------------------------------------------------------------------
template<bool SILU, bool BF16OUT, int RM>
__global__ __launch_bounds__(512, 1) void mm256_kernel(
    const unsigned short* __restrict__ A, const unsigned short* __restrict__ Bt,
    void* __restrict__ Cv, int M, int N, int K, int rows)
{
    int nwg = gridDim.x;
    int flat = blockIdx.x;
    int q8 = nwg >> 3, r8 = nwg & 7;
    int xcd = flat & 7, lid = flat >> 3;
    int wg = (r8 == 0) ? (xcd * q8 + lid)
           : ((xcd < r8 ? xcd * (q8 + 1) : r8 * (q8 + 1) + (xcd - r8) * q8) + lid);
    const int row0 = (wg % rows) * 256;
    const int col0 = (wg / rows) * 256;

    __shared__ __align__(16) char lds[131072];
    const int tid  = threadIdx.x;
    const int lane = tid & 63;
    const int wave = tid >> 6;
    const int wm = wave >> 2;
    const int wn = wave & 3;
    const int g  = lane >> 4;
    const int c  = lane & 15;

    f32x4 acc[8][4] = {};

    auto STAGE = [&](int buf, int tile) {
        const int k0 = tile * 32;
        char* base = lds + buf * 32768;
        #pragma unroll
        for (int j = 0; j < 2; ++j) {
            int chunk = j * 512 + tid;
            int row = chunk >> 2, slot = chunk & 3;
            int sslot = slot ^ ((row >> 1) & 3);
            __builtin_amdgcn_global_load_lds(
                (const __attribute__((address_space(1))) void*)
                    (A + (size_t)(row0 + row) * K + k0 + sslot * 8),
                (__attribute__((address_space(3))) void*)(base + chunk * 16), 16, 0, 0);
        }
        #pragma unroll
        for (int j = 0; j < 2; ++j) {
            int chunk = j * 512 + tid;
            int row = chunk >> 2, slot = chunk & 3;
            int sslot = slot ^ ((row >> 1) & 3);
            __builtin_amdgcn_global_load_lds(
                (const __attribute__((address_space(1))) void*)
                    (Bt + (size_t)(col0 + row) * K + k0 + sslot * 8),
                (__attribute__((address_space(3))) void*)(base + 16384 + chunk * 16), 16, 0, 0);
        }
    };

    const int NT = K >> 5;
    STAGE(0, 0); STAGE(1, 1); STAGE(2, 2);
    asm volatile("s_waitcnt vmcnt(8)" ::: "memory");
    __builtin_amdgcn_s_barrier();
    __builtin_amdgcn_sched_barrier(0);

    for (int t = 0; t < NT; ++t) {
        if (t + 3 < NT) STAGE((t + 3) & 3, t + 3);

        char* base = lds + (t & 3) * 32768;
        short8 af[8], bf[4];
        #pragma unroll
        for (int mf = 0; mf < 8; ++mf) {
            int row = wm * 128 + mf * 16 + c;
            af[mf] = *(const short8*)(base + row * 64 + ((g ^ ((row >> 1) & 3)) << 4));
        }
        #pragma unroll
        for (int nf = 0; nf < 4; ++nf) {
            int row = wn * 64 + nf * 16 + c;
            bf[nf] = *(const short8*)(base + 16384 + row * 64 + ((g ^ ((row >> 1) & 3)) << 4));
        }
        __builtin_amdgcn_s_setprio(1);
        #pragma unroll
        for (int mf = 0; mf < 8; ++mf)
            #pragma unroll
            for (int nf = 0; nf < 4; ++nf)
                acc[mf][nf] = __builtin_amdgcn_mfma_f32_16x16x32_bf16(
                    af[mf], bf[nf], acc[mf][nf], 0, 0, 0);
        __builtin_amdgcn_s_setprio(0);
        __builtin_amdgcn_sched_barrier(0);

        if (t + 1 < NT) {
            if (t + 3 < NT)      asm volatile("s_waitcnt vmcnt(8)" ::: "memory");
            else if (t + 2 < NT) asm volatile("s_waitcnt vmcnt(4)" ::: "memory");
            else                 asm volatile("s_waitcnt vmcnt(0)" ::: "memory");
            __builtin_amdgcn_s_barrier();
            __builtin_amdgcn_sched_barrier(0);
        }
    }

    float* Cf = (float*)Cv;
    unsigned short* Cb = (unsigned short*)Cv;
    #pragma unroll
    for (int mf = 0; mf < 8; ++mf) {
        #pragma unroll
        for (int nf = 0; nf < 4; ++nf) {
            int gcol = col0 + wn * 64 + nf * 16 + c;
            if (gcol < N) {
                #pragma unroll
                for (int r = 0; r < 4; ++r) {
                    int grow = row0 + wm * 128 + mf * 16 + g * 4 + r;
                    int orow = RM ? (((grow & (SEQ - 1)) << 1) | (grow >> 10)) : grow;
                    float v = acc[mf][nf][r];
                    if (SILU) v = v / (1.0f + __expf(-v));
                    size_t ci = (size_t)orow * N + gcol;
                    if (BF16OUT) Cb[ci] = f2bf(v);
                    else         Cf[ci] = v;
                }
            }
        }
    }
}

// ---------------------------------------------------------------------------
// Flash attention (bf16 MFMA). q,k from fused qkv (stride QKVLD); vt [hd][tok].
// ---------------------------------------------------------------------------
__global__ __launch_bounds__(256) void flash_attn_kernel(
    const unsigned short* __restrict__ q, const unsigned short* __restrict__ k,
    const unsigned short* __restrict__ vt, unsigned short* __restrict__ o)
{
    const int qt   = blockIdx.x;
    const int h    = blockIdx.y;
    const int b    = blockIdx.z;
    const int tid  = threadIdx.x;
    const int lane = tid & 63;
    const int wave = tid >> 6;
    const int g    = lane >> 4;
    const int c    = lane & 15;

    __shared__ unsigned short k_lds[64 * 128];
    __shared__ unsigned short vt_lds[128 * 64];
    __shared__ unsigned short p_lds[4 * 16 * 64];

    const int q0  = qt * 64;
    const int wq0 = q0 + wave * 16;
    const int tokb = b * SEQ;

    short8 qf[4];
    {
        const unsigned short* qr =
            q + (size_t)(tokb + wq0 + c) * QKVLD + h * HDIM + g * 8;
        #pragma unroll
        for (int dblk = 0; dblk < 4; ++dblk)
            qf[dblk] = *(const short8*)(qr + dblk * 32);
    }

    f32x4 oacc[8] = {};
    float m = -1e30f, l = 0.f;
    const float scale = 0.08838834764831845f;
    const int myq = wq0 + c;

    const int nt = qt + 1;
    for (int it = 0; it < nt; ++it) {
        const int kv0 = it * 64;
        short8 kc[4], vc[4];
        #pragma unroll
        for (int i = 0; i < 4; ++i) {
            int chunk = tid + i * 256;
            int key = chunk >> 4, cc = chunk & 15;
            kc[i] = *(const short8*)(
                k + (size_t)(tokb + kv0 + key) * QKVLD + h * HDIM + cc * 8);
        }
        #pragma unroll
        for (int i = 0; i < 4; ++i) {
            int chunk = tid + i * 256;
            int d = chunk >> 3, cc = chunk & 7;
            vc[i] = *(const short8*)(
                vt + (size_t)(h * HDIM + d) * NTOK + tokb + kv0 + cc * 8);
        }
        __syncthreads();
        #pragma unroll
        for (int i = 0; i < 4; ++i) {
            int chunk = tid + i * 256;
            int key = chunk >> 4, cc = chunk & 15;
            *(short8*)((char*)k_lds + ((key * 256 + cc * 16) ^ ((key & 7) << 4))) = kc[i];
        }
        #pragma unroll
        for (int i = 0; i < 4; ++i) {
            int chunk = tid + i * 256;
            int d = chunk >> 3, cc = chunk & 7;
            *(short8*)((char*)vt_lds + ((d * 128 + cc * 16) ^ ((d & 7) << 4))) = vc[i];
        }
        __syncthreads();

        f32x4 st[4];
        #pragma unroll
        for (int sub = 0; sub < 4; ++sub) {
            f32x4 acc = {};
            int key = sub * 16 + c;
            #pragma unroll
            for (int dblk = 0; dblk < 4; ++dblk) {
                short8 kf = *(const short8*)((char*)k_lds +
                    ((key * 256 + dblk * 64 + g * 16) ^ ((key & 7) << 4)));
                acc = __builtin_amdgcn_mfma_f32_16x16x32_bf16(kf, qf[dblk], acc, 0, 0, 0);
            }
            st[sub] = acc;
        }

        #pragma unroll
        for (int sub = 0; sub < 4; ++sub)
            #pragma unroll
            for (int r = 0; r < 4; ++r) {
                int key = kv0 + sub * 16 + g * 4 + r;
                float s = st[sub][r] * scale;
                st[sub][r] = (key <= myq) ? s : -1e30f;
            }

        float tm = -1e30f;
        #pragma unroll
        for (int sub = 0; sub < 4; ++sub)
            #pragma unroll
            for (int r = 0; r < 4; ++r) tm = fmaxf(tm, st[sub][r]);
        tm = fmaxf(tm, __shfl_xor(tm, 16));
        tm = fmaxf(tm, __shfl_xor(tm, 32));
        float mnew = fmaxf(m, tm);
        float sc_f = __expf(m - mnew);
        m = mnew;

        float ps = 0.f;
        #pragma unroll
        for (int sub = 0; sub < 4; ++sub) {
            float p0 = __expf(st[sub][0] - m);
            float p1 = __expf(st[sub][1] - m);
            float p2 = __expf(st[sub][2] - m);
            float p3 = __expf(st[sub][3] - m);
            ps += (p0 + p1) + (p2 + p3);
            ushort4 pk;
            pk.x = f2bf(p0); pk.y = f2bf(p1); pk.z = f2bf(p2); pk.w = f2bf(p3);
            *(ushort4*)((char*)p_lds + wave * 2048 +
                ((c * 128 + sub * 32 + g * 8) ^ ((c & 7) << 4))) = pk;
        }
        ps += __shfl_xor(ps, 16);
        ps += __shfl_xor(ps, 32);
        l = l * sc_f + ps;
        #pragma unroll
        for (int dt = 0; dt < 8; ++dt)
            #pragma unroll
            for (int r = 0; r < 4; ++r) oacc[dt][r] *= sc_f;

        #pragma unroll
        for (int kb = 0; kb < 2; ++kb) {
            short8 pf = *(const short8*)((char*)p_lds + wave * 2048 +
                ((c * 128 + kb * 64 + g * 16) ^ ((c & 7) << 4)));
            #pragma unroll
            for (int dt = 0; dt < 8; ++dt) {
                int d = dt * 16 + c;
                short8 vf = *(const short8*)((char*)vt_lds +
                    ((d * 128 + kb * 64 + g * 16) ^ ((d & 7) << 4)));
                oacc[dt] = __builtin_amdgcn_mfma_f32_16x16x32_bf16(vf, pf, oacc[dt], 0, 0, 0);
            }
        }
    }

    float inv = 1.0f / l;
    unsigned short* orow = o + (size_t)(tokb + wq0 + c) * DMODEL + h * HDIM + g * 4;
    #pragma unroll
    for (int dt = 0; dt < 8; ++dt) {
        ushort4 ov;
        ov.x = f2bf(oacc[dt][0] * inv);
        ov.y = f2bf(oacc[dt][1] * inv);
        ov.z = f2bf(oacc[dt][2] * inv);
        ov.w = f2bf(oacc[dt][3] * inv);
        *(ushort4*)(orow + dt * 16) = ov;
    }
}

// ---------------------------------------------------------------------------
// Launch
// ---------------------------------------------------------------------------
extern "C" void kernel_launch(void* const* d_in, const int* in_sizes, int n_in,
                              void* d_out, int out_size, void* d_ws, size_t ws_size,
                              hipStream_t stream)
{
    const int*   tokens       = (const int*)  d_in[0];
    const float* tok_emb      = (const float*)d_in[1];
    const float* pos_emb      = (const float*)d_in[2];
    const float* attn_norm_w  = (const float*)d_in[3];
    const float* Wq           = (const float*)d_in[4];
    const float* Wk           = (const float*)d_in[5];
    const float* Wv           = (const float*)d_in[6];
    const float* Wo           = (const float*)d_in[7];
    const float* mlp_norm_w   = (const float*)d_in[8];
    const float* W1           = (const float*)d_in[9];
    const float* W2           = (const float*)d_in[10];
    const float* final_norm_w = (const float*)d_in[11];
    float* out = (float*)d_out;

    // ---- workspace layout ----
    char* wp = (char*)d_ws;
    size_t off = 0;
    auto alloc = [&](size_t bytes) -> void* {
        void* p = wp + off;
        off += (bytes + 255) & ~(size_t)255;
        return p;
    };
    float* x             = (float*)alloc((size_t)NTOK * DMODEL * 4);
    unsigned short* nbf     = (unsigned short*)alloc((size_t)NTOK * DMODEL * 2);
    unsigned short* qkvbf   = (unsigned short*)alloc((size_t)NTOK * QKVLD * 2);
    unsigned short* vtb     = (unsigned short*)alloc((size_t)DMODEL * NTOK * 2);
    unsigned short* attnbf  = (unsigned short*)alloc((size_t)NTOK * DMODEL * 2);
    unsigned short* hbf     = (unsigned short*)alloc((size_t)NTOK * FFDIM * 2);
    unsigned short* temb    = (unsigned short*)alloc((size_t)VPAD * DMODEL * 2);
    unsigned short* Wqkv_t  = (unsigned short*)alloc((size_t)NLAYER * QKVLD * DMODEL * 2);
    unsigned short* Wo_t    = (unsigned short*)alloc((size_t)NLAYER * DMODEL * DMODEL * 2);
    unsigned short* W1_t    = (unsigned short*)alloc((size_t)NLAYER * DMODEL * FFDIM * 2);
    unsigned short* W2_t    = (unsigned short*)alloc((size_t)NLAYER * FFDIM * DMODEL * 2);
    if (off > ws_size) return;

    // ---- weight prep ----
    {
        dim3 bb(32, 8), g(HDIM / 32, DMODEL / 32, NLAYER * NHEAD);
        transpose_qkv_kernel<<<g, bb, 0, stream>>>(Wq, Wqkv_t, 0);
        transpose_qkv_kernel<<<g, bb, 0, stream>>>(Wk, Wqkv_t, DMODEL);
        transpose_qkv_kernel<<<g, bb, 0, stream>>>(Wv, Wqkv_t, 2 * DMODEL);
    }
    {
        dim3 bb(32, 8), g(DMODEL / 32, DMODEL / 32, NLAYER);
        transpose_cast_kernel<<<g, bb, 0, stream>>>(Wo, Wo_t, DMODEL, DMODEL);
    }
    {
        dim3 bb(32, 8), g(FFDIM / 32, DMODEL / 32, NLAYER);
        transpose_cast_kernel<<<g, bb, 0, stream>>>(W1, W1_t, DMODEL, FFDIM);
    }
    {
        dim3 bb(32, 8), g(DMODEL / 32, FFDIM / 32, NLAYER);
        transpose_cast_kernel<<<g, bb, 0, stream>>>(W2, W2_t, FFDIM, DMODEL);
    }
    {
        long n_src = (long)VOCAB * DMODEL, n_tot = (long)VPAD * DMODEL;
        cast_pad_kernel<<<(unsigned)(n_tot / 8 / 256), 256, 0, stream>>>(
            tok_emb, temb, n_src, n_tot);
    }

    // ---- embed ----
    embed_kernel<<<(NTOK * DMODEL) / 256, 256, 0, stream>>>(tokens, tok_emb, pos_emb, x);

    const size_t LW    = (size_t)DMODEL * DMODEL;
    const size_t LWQKV = (size_t)QKVLD * DMODEL;
    const size_t LWF   = (size_t)DMODEL * FFDIM;

    for (int l = 0; l < NLAYER; l++) {
        rmsnorm_bf_kernel<<<NTOK, 256, 0, stream>>>(x, attn_norm_w + (size_t)l * DMODEL, nbf);
        // fused qkv: [NTOK][3072], 24 cols x 16 rows = 384 blocks
        mm128_kernel<false, false, true><<<384, 256, 0, stream>>>(
            nbf, Wqkv_t + l * LWQKV, qkvbf, NTOK, QKVLD, DMODEL, 16, 1);
        vt_transpose_kernel<<<dim3(DMODEL / 32, NTOK / 32), dim3(32, 8), 0, stream>>>(
            qkvbf, vtb);
        flash_attn_kernel<<<dim3(SEQ / 64, NHEAD, BATCH), 256, 0, stream>>>(
            qkvbf, qkvbf + DMODEL, vtb, attnbf);
        // out proj: split-K=2, atomic f32 accumulate into residual x
        mm128_kernel<true, false, false><<<8 * 16 * 2, 256, 0, stream>>>(
            attnbf, Wo_t + l * LW, x, NTOK, DMODEL, DMODEL, 16, 2);
        rmsnorm_bf_kernel<<<NTOK, 256, 0, stream>>>(x, mlp_norm_w + (size_t)l * DMODEL, nbf);
        // h = silu(n @ W1): 32 cols x 16 rows = 512 blocks
        mm128_kernel<false, true, true><<<32 * 16, 256, 0, stream>>>(
            nbf, W1_t + l * LWF, hbf, NTOK, FFDIM, DMODEL, 16, 1);
        // x += h @ W2: split-K=2
        mm128_kernel<true, false, false><<<8 * 16 * 2, 256, 0, stream>>>(
            hbf, W2_t + l * LWF, x, NTOK, DMODEL, FFDIM, 16, 2);
    }

    rmsnorm_bf_kernel<<<NTOK, 256, 0, stream>>>(x, final_norm_w, nbf);
    // lm-head: 256-tile kernel, 8 rows x 197 cols = 1576 blocks
    mm256_kernel<false, false, 1><<<8 * 197, 512, 0, stream>>>(
        nbf, temb, out, NTOK, VOCAB, DMODEL, 8);
}